// Round 1
// baseline (607.442 us; speedup 1.0000x reference)
//
#include <hip/hip_runtime.h>
#include <hip/hip_bf16.h>
#include <hip/hip_fp16.h>

// Problem constants
#define B_ 2
#define N_ 40962
#define D_ 128
#define H_ 4
#define P_ 100
#define S_ 512
#define T_ 102400      // B*P*S tokens
#define PS_ 51200      // P*S

typedef unsigned short u16;
typedef unsigned int u32;
typedef _Float16 f16x4 __attribute__((ext_vector_type(4)));
typedef float f32x4 __attribute__((ext_vector_type(4)));

// Workspace byte offsets (total ~79.2 MB)
#define OFF_Q    0ull           // q fp16 [T][128]  (later reused as att)
#define OFF_K    26214400ull    // k fp16 [T][128]
#define OFF_V    52428800ull    // v fp16 [T][128]
#define OFF_BP   78643200ull    // packed W frags: 4 mats x 4096 lane-frags x 8B
#define OFF_CNT  78774272ull    // float cnt[N]
#define OFF_CM   78938120ull    // float cm[P*S]
#define OFF_FLAG 79142920ull    // int dtype flag for core_mask

__device__ __forceinline__ u32 pack2h(float a, float b) {
  __half2 h = __floats2half2_rn(a, b);
  return __builtin_bit_cast(u32, h);
}
__device__ __forceinline__ float2 unpack2h(u32 u) {
  __half2 h = __builtin_bit_cast(__half2, u);
  return __half22float2(h);
}
__device__ __forceinline__ void unpack8h(uint4 u, float* o, float sc) {
  float2 f;
  f = unpack2h(u.x); o[0] = f.x * sc; o[1] = f.y * sc;
  f = unpack2h(u.y); o[2] = f.x * sc; o[3] = f.y * sc;
  f = unpack2h(u.z); o[4] = f.x * sc; o[5] = f.y * sc;
  f = unpack2h(u.w); o[6] = f.x * sc; o[7] = f.y * sc;
}

// ---------------------------------------------------------------------------
// Probe core_mask storage format. bool8 -> bytes at off%4==1 are ~80% nonzero.
// int32 (0/1) -> bytes at off%4 in {1,2,3} always 0. float32 (0.0/1.0) ->
// byte off%4==1 always 0, off%4==3 is 0x3f for 1.0f.  flag bit0 => bool8,
// bit1 => float32, neither => int32.
__global__ void probe_mask_k(const unsigned char* __restrict__ mb, int* __restrict__ flag) {
  int f = 0;
  for (int i = threadIdx.x; i < PS_; i += 256) {
    unsigned char v = mb[i];
    if (v) {
      int m4 = i & 3;
      if (m4 == 1) f |= 1;
      else if (m4 == 3) f |= 2;
    }
  }
  if (f) atomicOr(flag, f);
}

// cm[i] = mask as float; cnt[n] += cm  (exact small-int fp32 adds)
__global__ void mask_cnt_k(const void* __restrict__ mask, const int* __restrict__ pidx,
                           const int* __restrict__ flag, float* __restrict__ cm,
                           float* __restrict__ cnt) {
  int i = blockIdx.x * 256 + threadIdx.x;
  int fl = *flag;
  bool on;
  if (fl & 1)      on = ((const unsigned char*)mask)[i] != 0;
  else if (fl & 2) on = ((const float*)mask)[i] != 0.f;
  else             on = ((const int*)mask)[i] != 0;
  cm[i] = on ? 1.f : 0.f;
  if (on) atomicAdd(&cnt[pidx[i]], 1.f);
}

// ---------------------------------------------------------------------------
// Pack Wq/Wk/Wv/Wo into MFMA B-fragment order (fp16).
// out[t,n] = sum_k in[t,k] * W[n,k]  => Bmat[k][n] = W[n][k].
// Frag for (mat m, ntile nt, kstep ks, lane l), elem i (0..3):
//   B[ks*16 + 4*(l>>4) + i][nt*16 + (l&15)] = W[nt*16+(l&15)][ks*16+4*(l>>4)+i]
// i walks a W row contiguously -> one float4 read per lane-frag.
__global__ void pack_w_k(const float* __restrict__ Wq, const float* __restrict__ Wk,
                         const float* __restrict__ Wv, const float* __restrict__ Wo,
                         u16* __restrict__ bp) {
  int gi = blockIdx.x * 256 + threadIdx.x;   // < 16384
  int m = gi >> 12;
  int r = gi & 4095;
  int fi = r >> 6;         // nt*8 + ks
  int l = r & 63;
  int nt = fi >> 3, ks = fi & 7;
  const float* W = (m == 0) ? Wq : (m == 1) ? Wk : (m == 2) ? Wv : Wo;
  int n = nt * 16 + (l & 15);
  int k0 = ks * 16 + ((l >> 4) << 2);
  float4 w = *(const float4*)(W + n * 128 + k0);
  *(uint2*)(bp + (size_t)gi * 4) = make_uint2(pack2h(w.x, w.y), pack2h(w.z, w.w));
}

// ---------------------------------------------------------------------------
// Gather px rows + QKV projection GEMM (M=T, N=128 per mat, K=128), MFMA f16.
// grid (1600, 3): y selects q/k/v. Block: 64 tokens x 128 cols, 4 waves (2x2).
__global__ __launch_bounds__(256) void qkv_k(
    const float* __restrict__ x, const int* __restrict__ pidx,
    const u16* __restrict__ bp,
    const float* __restrict__ bq, const float* __restrict__ bk, const float* __restrict__ bv,
    u16* __restrict__ qkv) {
  __shared__ uint4 As[64 * 16];   // 64 rows x 128 fp16, XOR-swizzled (G4)
  int tid = threadIdx.x;
  int mat = blockIdx.y;
  int t0 = blockIdx.x * 64;
  {
    int r = tid >> 2, qd = tid & 3;
    int T = t0 + r;
    int b = T / PS_;
    int ps = T - b * PS_;                   // == p*S + s
    int pi = pidx[ps];
    const float4* src = (const float4*)(x + ((size_t)b * N_ + pi) * D_ + qd * 32);
    u32 us[16];
#pragma unroll
    for (int j = 0; j < 8; j++) {
      float4 f = src[j];
      us[2 * j]     = pack2h(f.x, f.y);
      us[2 * j + 1] = pack2h(f.z, f.w);
    }
#pragma unroll
    for (int c = 0; c < 4; c++) {
      int byteoff = (qd * 64 + c * 16) ^ ((r & 7) << 4);
      As[r * 16 + (byteoff >> 4)] = make_uint4(us[4 * c], us[4 * c + 1], us[4 * c + 2], us[4 * c + 3]);
    }
  }
  __syncthreads();
  int lane = tid & 63, wid = tid >> 6;
  int wm = wid & 1, wn = wid >> 1;          // wave = 32 tokens x 64 cols
  uint2 bfrag[4][8];
  const uint2* bpp = (const uint2*)bp;
#pragma unroll
  for (int nt = 0; nt < 4; nt++) {
    int ntg = wn * 4 + nt;
#pragma unroll
    for (int ks = 0; ks < 8; ks++)
      bfrag[nt][ks] = bpp[(mat * 64 + ntg * 8 + ks) * 64 + lane];
  }
  const float* bias = (mat == 0) ? bq : (mat == 1) ? bk : bv;
  f32x4 acc[2][4];
#pragma unroll
  for (int nt = 0; nt < 4; nt++) {
    float bvv = bias[wn * 64 + nt * 16 + (lane & 15)];
#pragma unroll
    for (int mt = 0; mt < 2; mt++) {
      f32x4 z = {bvv, bvv, bvv, bvv};
      acc[mt][nt] = z;
    }
  }
  uint2 afr[2][8];
#pragma unroll
  for (int mt = 0; mt < 2; mt++) {
    int row = wm * 32 + mt * 16 + (lane & 15);
#pragma unroll
    for (int ks = 0; ks < 8; ks++) {
      int byteoff = (ks * 32 + ((lane >> 4) << 3)) ^ ((row & 7) << 4);
      afr[mt][ks] = *(const uint2*)((const char*)As + row * 256 + byteoff);
    }
  }
#pragma unroll
  for (int ks = 0; ks < 8; ks++) {
#pragma unroll
    for (int mt = 0; mt < 2; mt++) {
      f16x4 a = __builtin_bit_cast(f16x4, afr[mt][ks]);
#pragma unroll
      for (int nt = 0; nt < 4; nt++) {
        f16x4 b = __builtin_bit_cast(f16x4, bfrag[nt][ks]);
        acc[mt][nt] = __builtin_amdgcn_mfma_f32_16x16x16f16(a, b, acc[mt][nt], 0, 0, 0);
      }
    }
  }
  u16* outp = qkv + (size_t)mat * T_ * D_;
#pragma unroll
  for (int mt = 0; mt < 2; mt++) {
    int rbase = t0 + wm * 32 + mt * 16 + ((lane >> 4) << 2);
#pragma unroll
    for (int nt = 0; nt < 4; nt++) {
      int col = wn * 64 + nt * 16 + (lane & 15);
#pragma unroll
      for (int i = 0; i < 4; i++) {
        __half hv = __float2half(acc[mt][nt][i]);
        outp[(size_t)(rbase + i) * D_ + col] = __builtin_bit_cast(u16, hv);
      }
    }
  }
}

// ---------------------------------------------------------------------------
// Attention per (b,p,h): 800 blocks x 256 threads; each thread owns q-rows
// tid and tid+256. Single-pass softmax without max subtraction (scores are
// O(+-10); exp cannot overflow fp32). K/V staged per 64-row tile in LDS fp32
// with a float4-level XOR swizzle; inner reads are wave-uniform (broadcast).
// att overwrites the q workspace (q is register-resident before first barrier).
__global__ __launch_bounds__(256) void attn_k(
    u16* wq_att, const u16* __restrict__ wk, const u16* __restrict__ wv) {
  __shared__ float4 kt[64 * 8];
  __shared__ float4 vt[64 * 8];
  int tid = threadIdx.x;
  int bid = blockIdx.x;
  int h = bid & (H_ - 1);
  int bp = bid >> 2;                 // b*P + p
  size_t tb = (size_t)bp * S_;
  const float scale = 0.17677669529663687f;   // 1/sqrt(32)
  float q0[32], q1[32], a0[32], a1[32];
  {
    const uint4* p0 = (const uint4*)(wq_att + (tb + tid) * D_ + h * 32);
    const uint4* p1 = (const uint4*)(wq_att + (tb + tid + 256) * D_ + h * 32);
#pragma unroll
    for (int c = 0; c < 4; c++) {
      unpack8h(p0[c], &q0[c * 8], scale);
      unpack8h(p1[c], &q1[c * 8], scale);
    }
  }
#pragma unroll
  for (int c = 0; c < 32; c++) { a0[c] = 0.f; a1[c] = 0.f; }
  float l0 = 0.f, l1 = 0.f;
  int rr = tid >> 2, part = tid & 3;
  int sw = (rr & 3) * 2;
  for (int t = 0; t < S_; t += 64) {
    __syncthreads();   // previous tile fully consumed
    {
      size_t ro = (tb + t + rr) * D_ + h * 32 + part * 8;
      uint4 ku = *(const uint4*)(wk + ro);
      uint4 vu = *(const uint4*)(wv + ro);
      float kf[8], vf[8];
      unpack8h(ku, kf, 1.f);
      unpack8h(vu, vf, 1.f);
      kt[rr * 8 + ((part * 2 + 0) ^ sw)] = make_float4(kf[0], kf[1], kf[2], kf[3]);
      kt[rr * 8 + ((part * 2 + 1) ^ sw)] = make_float4(kf[4], kf[5], kf[6], kf[7]);
      vt[rr * 8 + ((part * 2 + 0) ^ sw)] = make_float4(vf[0], vf[1], vf[2], vf[3]);
      vt[rr * 8 + ((part * 2 + 1) ^ sw)] = make_float4(vf[4], vf[5], vf[6], vf[7]);
    }
    __syncthreads();
    for (int kk = 0; kk < 64; kk++) {
      int fb = kk * 8, sw2 = (kk & 3) * 2;
      float4 kr[8];
#pragma unroll
      for (int j = 0; j < 8; j++) kr[j] = kt[fb + (j ^ sw2)];
      float s0a = 0.f, s0b = 0.f, s0c = 0.f, s0d = 0.f;
      float s1a = 0.f, s1b = 0.f, s1c = 0.f, s1d = 0.f;
#pragma unroll
      for (int j = 0; j < 8; j++) {
        s0a = fmaf(q0[j * 4 + 0], kr[j].x, s0a);
        s0b = fmaf(q0[j * 4 + 1], kr[j].y, s0b);
        s0c = fmaf(q0[j * 4 + 2], kr[j].z, s0c);
        s0d = fmaf(q0[j * 4 + 3], kr[j].w, s0d);
        s1a = fmaf(q1[j * 4 + 0], kr[j].x, s1a);
        s1b = fmaf(q1[j * 4 + 1], kr[j].y, s1b);
        s1c = fmaf(q1[j * 4 + 2], kr[j].z, s1c);
        s1d = fmaf(q1[j * 4 + 3], kr[j].w, s1d);
      }
      float e0 = __expf((s0a + s0b) + (s0c + s0d));
      float e1 = __expf((s1a + s1b) + (s1c + s1d));
      l0 += e0; l1 += e1;
      float4 vr[8];
#pragma unroll
      for (int j = 0; j < 8; j++) vr[j] = vt[fb + (j ^ sw2)];
#pragma unroll
      for (int j = 0; j < 8; j++) {
        a0[j * 4 + 0] = fmaf(e0, vr[j].x, a0[j * 4 + 0]);
        a0[j * 4 + 1] = fmaf(e0, vr[j].y, a0[j * 4 + 1]);
        a0[j * 4 + 2] = fmaf(e0, vr[j].z, a0[j * 4 + 2]);
        a0[j * 4 + 3] = fmaf(e0, vr[j].w, a0[j * 4 + 3]);
        a1[j * 4 + 0] = fmaf(e1, vr[j].x, a1[j * 4 + 0]);
        a1[j * 4 + 1] = fmaf(e1, vr[j].y, a1[j * 4 + 1]);
        a1[j * 4 + 2] = fmaf(e1, vr[j].z, a1[j * 4 + 2]);
        a1[j * 4 + 3] = fmaf(e1, vr[j].w, a1[j * 4 + 3]);
      }
    }
  }
  float r0 = 1.f / l0, r1 = 1.f / l1;
  u32* o0 = (u32*)(wq_att + (tb + tid) * D_ + h * 32);
  u32* o1 = (u32*)(wq_att + (tb + tid + 256) * D_ + h * 32);
#pragma unroll
  for (int c = 0; c < 16; c++) {
    o0[c] = pack2h(a0[2 * c] * r0, a0[2 * c + 1] * r0);
    o1[c] = pack2h(a1[2 * c] * r1, a1[2 * c + 1] * r1);
  }
}

// ---------------------------------------------------------------------------
// Output projection (att @ Wo^T + bo) * cm, scatter-add into out (=agg).
__global__ __launch_bounds__(256) void proj_k(
    const u16* __restrict__ watt, const u16* __restrict__ bp, const float* __restrict__ bo,
    const int* __restrict__ pidx, const float* __restrict__ cm, float* __restrict__ out) {
  __shared__ uint4 As[64 * 16];
  __shared__ int pis[64];
  __shared__ float cms[64];
  int tid = threadIdx.x;
  int t0 = blockIdx.x * 64;
  {
    int r = tid >> 2, qd = tid & 3;
    int T = t0 + r;
    int b = T / PS_;
    int ps = T - b * PS_;
    if (qd == 0) { pis[r] = b * N_ + pidx[ps]; cms[r] = cm[ps]; }
    const uint4* src = (const uint4*)(watt + (size_t)T * D_ + qd * 32);
#pragma unroll
    for (int c = 0; c < 4; c++) {
      int byteoff = (qd * 64 + c * 16) ^ ((r & 7) << 4);
      As[r * 16 + (byteoff >> 4)] = src[c];
    }
  }
  __syncthreads();
  int lane = tid & 63, wid = tid >> 6;
  int wm = wid & 1, wn = wid >> 1;
  uint2 bfrag[4][8];
  const uint2* bpp = (const uint2*)bp;
#pragma unroll
  for (int nt = 0; nt < 4; nt++) {
    int ntg = wn * 4 + nt;
#pragma unroll
    for (int ks = 0; ks < 8; ks++)
      bfrag[nt][ks] = bpp[(3 * 64 + ntg * 8 + ks) * 64 + lane];
  }
  f32x4 acc[2][4];
#pragma unroll
  for (int mt = 0; mt < 2; mt++)
#pragma unroll
    for (int nt = 0; nt < 4; nt++) {
      f32x4 z = {0.f, 0.f, 0.f, 0.f};
      acc[mt][nt] = z;
    }
  uint2 afr[2][8];
#pragma unroll
  for (int mt = 0; mt < 2; mt++) {
    int row = wm * 32 + mt * 16 + (lane & 15);
#pragma unroll
    for (int ks = 0; ks < 8; ks++) {
      int byteoff = (ks * 32 + ((lane >> 4) << 3)) ^ ((row & 7) << 4);
      afr[mt][ks] = *(const uint2*)((const char*)As + row * 256 + byteoff);
    }
  }
#pragma unroll
  for (int ks = 0; ks < 8; ks++) {
#pragma unroll
    for (int mt = 0; mt < 2; mt++) {
      f16x4 a = __builtin_bit_cast(f16x4, afr[mt][ks]);
#pragma unroll
      for (int nt = 0; nt < 4; nt++) {
        f16x4 b = __builtin_bit_cast(f16x4, bfrag[nt][ks]);
        acc[mt][nt] = __builtin_amdgcn_mfma_f32_16x16x16f16(a, b, acc[mt][nt], 0, 0, 0);
      }
    }
  }
#pragma unroll
  for (int mt = 0; mt < 2; mt++) {
    int rl = wm * 32 + mt * 16 + ((lane >> 4) << 2);
#pragma unroll
    for (int nt = 0; nt < 4; nt++) {
      int col = wn * 64 + nt * 16 + (lane & 15);
      float bov = bo[col];
#pragma unroll
      for (int i = 0; i < 4; i++) {
        float cmv = cms[rl + i];
        if (cmv != 0.f) {
          float val = (acc[mt][nt][i] + bov) * cmv;
          atomicAdd(out + (size_t)pis[rl + i] * D_ + col, val);
        }
      }
    }
  }
}

// ---------------------------------------------------------------------------
// h = x + agg/max(cnt,1); LayerNorm over D; in-place on out. 32 lanes per row.
__global__ __launch_bounds__(256) void ln_k(
    const float* __restrict__ x, const float* __restrict__ cnt,
    const float* __restrict__ g, const float* __restrict__ bta, float* __restrict__ out) {
  int tid = threadIdx.x;
  int row = blockIdx.x * 8 + (tid >> 5);
  if (row >= B_ * N_) return;
  int l32 = tid & 31;
  int n = row % N_;
  float c = cnt[n];
  c = c > 1.f ? c : 1.f;
  float rc = 1.f / c;
  size_t off = (size_t)row * D_ + l32 * 4;
  float4 xa = *(const float4*)(x + off);
  float4 ag = *(const float4*)(out + off);
  float4 hv = make_float4(fmaf(ag.x, rc, xa.x), fmaf(ag.y, rc, xa.y),
                          fmaf(ag.z, rc, xa.z), fmaf(ag.w, rc, xa.w));
  float s = hv.x + hv.y + hv.z + hv.w;
  float s2 = hv.x * hv.x + hv.y * hv.y + hv.z * hv.z + hv.w * hv.w;
#pragma unroll
  for (int m = 16; m >= 1; m >>= 1) {
    s += __shfl_xor(s, m);
    s2 += __shfl_xor(s2, m);
  }
  float mu = s * 0.0078125f;
  float var = s2 * 0.0078125f - mu * mu;
  float rstd = rsqrtf(var + 1e-5f);
  float4 gv = *(const float4*)(g + l32 * 4);
  float4 bv = *(const float4*)(bta + l32 * 4);
  float4 ov = make_float4((hv.x - mu) * rstd * gv.x + bv.x,
                          (hv.y - mu) * rstd * gv.y + bv.y,
                          (hv.z - mu) * rstd * gv.z + bv.z,
                          (hv.w - mu) * rstd * gv.w + bv.w);
  *(float4*)(out + off) = ov;
}

// ---------------------------------------------------------------------------
extern "C" void kernel_launch(void* const* d_in, const int* in_sizes, int n_in,
                              void* d_out, int out_size, void* d_ws, size_t ws_size,
                              hipStream_t stream) {
  const float* x   = (const float*)d_in[0];
  const float* Wq  = (const float*)d_in[1];
  const float* bq  = (const float*)d_in[2];
  const float* Wk  = (const float*)d_in[3];
  const float* bk  = (const float*)d_in[4];
  const float* Wv  = (const float*)d_in[5];
  const float* bv  = (const float*)d_in[6];
  const float* Wo  = (const float*)d_in[7];
  const float* bo  = (const float*)d_in[8];
  const float* lng = (const float*)d_in[9];
  const float* lnb = (const float*)d_in[10];
  const int* pidx  = (const int*)d_in[11];
  const void* cmask = d_in[12];
  float* out = (float*)d_out;
  char* ws = (char*)d_ws;

  u16* wsq = (u16*)(ws + OFF_Q);
  u16* wsk = (u16*)(ws + OFF_K);
  u16* wsv = (u16*)(ws + OFF_V);
  u16* wbp = (u16*)(ws + OFF_BP);
  float* wcnt = (float*)(ws + OFF_CNT);
  float* wcm  = (float*)(ws + OFF_CM);
  int* wflag  = (int*)(ws + OFF_FLAG);

  hipMemsetAsync(d_out, 0, (size_t)out_size * sizeof(float), stream);
  hipMemsetAsync(ws + OFF_CNT, 0, (OFF_FLAG + 4) - OFF_CNT, stream);

  probe_mask_k<<<1, 256, 0, stream>>>((const unsigned char*)cmask, wflag);
  mask_cnt_k<<<200, 256, 0, stream>>>(cmask, pidx, wflag, wcm, wcnt);
  pack_w_k<<<64, 256, 0, stream>>>(Wq, Wk, Wv, Wo, wbp);
  qkv_k<<<dim3(1600, 3), 256, 0, stream>>>(x, pidx, wbp, bq, bk, bv, wsq);
  attn_k<<<800, 256, 0, stream>>>(wsq, wsk, wsv);
  proj_k<<<1600, 256, 0, stream>>>(wsq, wbp, bo, pidx, wcm, out);
  ln_k<<<10241, 256, 0, stream>>>(x, wcnt, lng, lnb, out);
}

// Round 2
// 257.676 us; speedup vs baseline: 2.3574x; 2.3574x over previous
//
#include <hip/hip_runtime.h>
#include <hip/hip_bf16.h>
#include <hip/hip_fp16.h>

// Problem constants
#define B_ 2
#define N_ 40962
#define D_ 128
#define H_ 4
#define P_ 100
#define S_ 512
#define T_ 102400      // B*P*S tokens
#define PS_ 51200      // P*S

typedef unsigned short u16;
typedef unsigned int u32;
typedef _Float16 f16x4 __attribute__((ext_vector_type(4)));
typedef float f32x4 __attribute__((ext_vector_type(4)));

// Workspace byte offsets (total ~79.2 MB)
#define OFF_Q    0ull           // q fp16 [T][128]  (later reused as att)
#define OFF_K    26214400ull    // k fp16 [T][128]
#define OFF_V    52428800ull    // v fp16 V^T: [bp*4+h][32][512]
#define OFF_BP   78643200ull    // packed W frags: 4 mats x 4096 lane-frags x 8B
#define OFF_CNT  78774272ull    // float cnt[N]
#define OFF_CM   78938120ull    // float cm[P*S]
#define OFF_FLAG 79142920ull    // int dtype flag for core_mask

__device__ __forceinline__ u32 pack2h(float a, float b) {
  __half2 h = __floats2half2_rn(a, b);
  return __builtin_bit_cast(u32, h);
}
__device__ __forceinline__ float2 unpack2h(u32 u) {
  __half2 h = __builtin_bit_cast(__half2, u);
  return __half22float2(h);
}

// ---------------------------------------------------------------------------
// Probe core_mask storage format (bool8 / int32 / float32) — see round 0.
__global__ void probe_mask_k(const unsigned char* __restrict__ mb, int* __restrict__ flag) {
  int f = 0;
  for (int i = threadIdx.x; i < PS_; i += 256) {
    unsigned char v = mb[i];
    if (v) {
      int m4 = i & 3;
      if (m4 == 1) f |= 1;
      else if (m4 == 3) f |= 2;
    }
  }
  if (f) atomicOr(flag, f);
}

// cm[i] = mask as float; cnt[n] += cm
__global__ void mask_cnt_k(const void* __restrict__ mask, const int* __restrict__ pidx,
                           const int* __restrict__ flag, float* __restrict__ cm,
                           float* __restrict__ cnt) {
  int i = blockIdx.x * 256 + threadIdx.x;
  int fl = *flag;
  bool on;
  if (fl & 1)      on = ((const unsigned char*)mask)[i] != 0;
  else if (fl & 2) on = ((const float*)mask)[i] != 0.f;
  else             on = ((const int*)mask)[i] != 0;
  cm[i] = on ? 1.f : 0.f;
  if (on) atomicAdd(&cnt[pidx[i]], 1.f);
}

// ---------------------------------------------------------------------------
// Pack Wq/Wk/Wv/Wo into MFMA B-fragment order (fp16). See round 0.
__global__ void pack_w_k(const float* __restrict__ Wq, const float* __restrict__ Wk,
                         const float* __restrict__ Wv, const float* __restrict__ Wo,
                         u16* __restrict__ bp) {
  int gi = blockIdx.x * 256 + threadIdx.x;   // < 16384
  int m = gi >> 12;
  int r = gi & 4095;
  int fi = r >> 6;         // nt*8 + ks
  int l = r & 63;
  int nt = fi >> 3, ks = fi & 7;
  const float* W = (m == 0) ? Wq : (m == 1) ? Wk : (m == 2) ? Wv : Wo;
  int n = nt * 16 + (l & 15);
  int k0 = ks * 16 + ((l >> 4) << 2);
  float4 w = *(const float4*)(W + n * 128 + k0);
  *(uint2*)(bp + (size_t)gi * 4) = make_uint2(pack2h(w.x, w.y), pack2h(w.z, w.w));
}

// ---------------------------------------------------------------------------
// Gather px rows + QKV projection GEMM. mat 0/1 -> [T][128]; mat 2 -> V^T
// layout [bp*4+h][hd=32][s=512] so attention's PV A-frag is a contiguous read.
__global__ __launch_bounds__(256) void qkv_k(
    const float* __restrict__ x, const int* __restrict__ pidx,
    const u16* __restrict__ bp,
    const float* __restrict__ bq, const float* __restrict__ bk, const float* __restrict__ bv,
    u16* __restrict__ qkv) {
  __shared__ uint4 As[64 * 16];   // 64 rows x 128 fp16, XOR-swizzled
  int tid = threadIdx.x;
  int mat = blockIdx.y;
  int t0 = blockIdx.x * 64;
  {
    int r = tid >> 2, qd = tid & 3;
    int T = t0 + r;
    int b = T / PS_;
    int ps = T - b * PS_;
    int pi = pidx[ps];
    const float4* src = (const float4*)(x + ((size_t)b * N_ + pi) * D_ + qd * 32);
    u32 us[16];
#pragma unroll
    for (int j = 0; j < 8; j++) {
      float4 f = src[j];
      us[2 * j]     = pack2h(f.x, f.y);
      us[2 * j + 1] = pack2h(f.z, f.w);
    }
#pragma unroll
    for (int c = 0; c < 4; c++) {
      int byteoff = (qd * 64 + c * 16) ^ ((r & 7) << 4);
      As[r * 16 + (byteoff >> 4)] = make_uint4(us[4 * c], us[4 * c + 1], us[4 * c + 2], us[4 * c + 3]);
    }
  }
  __syncthreads();
  int lane = tid & 63, wid = tid >> 6;
  int l15 = lane & 15, l4 = lane >> 4;
  int wm = wid & 1, wn = wid >> 1;
  uint2 bfrag[4][8];
  const uint2* bpp = (const uint2*)bp;
#pragma unroll
  for (int nt = 0; nt < 4; nt++) {
    int ntg = wn * 4 + nt;
#pragma unroll
    for (int ks = 0; ks < 8; ks++)
      bfrag[nt][ks] = bpp[(mat * 64 + ntg * 8 + ks) * 64 + lane];
  }
  const float* bias = (mat == 0) ? bq : (mat == 1) ? bk : bv;
  f32x4 acc[2][4];
#pragma unroll
  for (int nt = 0; nt < 4; nt++) {
    float bvv = bias[wn * 64 + nt * 16 + l15];
#pragma unroll
    for (int mt = 0; mt < 2; mt++) {
      f32x4 z = {bvv, bvv, bvv, bvv};
      acc[mt][nt] = z;
    }
  }
  uint2 afr[2][8];
#pragma unroll
  for (int mt = 0; mt < 2; mt++) {
    int row = wm * 32 + mt * 16 + l15;
#pragma unroll
    for (int ks = 0; ks < 8; ks++) {
      int byteoff = (ks * 32 + (l4 << 3)) ^ ((row & 7) << 4);
      afr[mt][ks] = *(const uint2*)((const char*)As + row * 256 + byteoff);
    }
  }
#pragma unroll
  for (int ks = 0; ks < 8; ks++) {
#pragma unroll
    for (int mt = 0; mt < 2; mt++) {
      f16x4 a = __builtin_bit_cast(f16x4, afr[mt][ks]);
#pragma unroll
      for (int nt = 0; nt < 4; nt++) {
        f16x4 b = __builtin_bit_cast(f16x4, bfrag[nt][ks]);
        acc[mt][nt] = __builtin_amdgcn_mfma_f32_16x16x16f16(a, b, acc[mt][nt], 0, 0, 0);
      }
    }
  }
  if (mat == 2) {
    u16* vt = qkv + (size_t)2 * T_ * D_;
#pragma unroll
    for (int mt = 0; mt < 2; mt++) {
      int rbase = t0 + wm * 32 + mt * 16 + (l4 << 2);
      int bpi = rbase >> 9;        // b*P + p (same for all 4 i)
      int s = rbase & 511;
#pragma unroll
      for (int nt = 0; nt < 4; nt++) {
        int col = wn * 64 + nt * 16 + l15;
        uint2 pv = make_uint2(pack2h(acc[mt][nt][0], acc[mt][nt][1]),
                              pack2h(acc[mt][nt][2], acc[mt][nt][3]));
        *(uint2*)(vt + ((size_t)(bpi * 4 + (col >> 5)) * 32 + (col & 31)) * 512 + s) = pv;
      }
    }
  } else {
    u16* outp = qkv + (size_t)mat * T_ * D_;
#pragma unroll
    for (int mt = 0; mt < 2; mt++) {
      int rbase = t0 + wm * 32 + mt * 16 + (l4 << 2);
#pragma unroll
      for (int nt = 0; nt < 4; nt++) {
        int col = wn * 64 + nt * 16 + l15;
#pragma unroll
        for (int i = 0; i < 4; i++) {
          __half hv = __float2half(acc[mt][nt][i]);
          outp[(size_t)(rbase + i) * D_ + col] = __builtin_bit_cast(u16, hv);
        }
      }
    }
  }
}

// ---------------------------------------------------------------------------
// MFMA flash-attention with swapped operands.
// Block = 256 thr (4 waves), one (bp, h, q-half); wave owns 64 q-rows.
// S^T = mfma(K, Q): lane holds S^T[k = mt*16+4*l4+i][q = nt*16+l15] -> exp'd
// + packed f16 in-lane == exact B-operand of O^T = mfma(V^T, P^T).
// No max-subtraction (scores O(+-6), validated round 0/1); l-sum reduced by
// two shfl_xor at the end. K/V staged in LDS with 8B-granule XOR swizzle.
__global__ __launch_bounds__(256) void attn_k(
    u16* wq_att, const u16* __restrict__ wk, const u16* __restrict__ wvt) {
  __shared__ __align__(16) u16 Ks[64 * 32];   // [k-row][32 hd], granule-swizzled
  __shared__ __align__(16) u16 Vs[32 * 64];   // [hd][64 k], granule-swizzled
  int tid = threadIdx.x;
  int bid = blockIdx.x;
  int bp = bid >> 3;
  int h = (bid >> 1) & 3;
  int qh = bid & 1;
  int lane = tid & 63, w = tid >> 6;
  int l15 = lane & 15, l4 = lane >> 4;
  size_t tbase = (size_t)bp * 512;
  int q0 = qh * 256 + w * 64;
  // Q B-frags [ks][nt]: Q[q0+nt*16+l15][h*32 + ks*16 + 4*l4 .. +3]
  uint2 qf[2][4];
  {
    const u16* qbase = wq_att + (tbase + q0) * 128 + h * 32;
#pragma unroll
    for (int nt = 0; nt < 4; nt++)
#pragma unroll
      for (int ks = 0; ks < 2; ks++)
        qf[ks][nt] = *(const uint2*)(qbase + (size_t)(nt * 16 + l15) * 128 + ks * 16 + l4 * 4);
  }
  f32x4 O[2][4];
#pragma unroll
  for (int a = 0; a < 2; a++)
#pragma unroll
    for (int b = 0; b < 4; b++) O[a][b] = (f32x4){0.f, 0.f, 0.f, 0.f};
  float lsum[4] = {0.f, 0.f, 0.f, 0.f};
  int sr = tid >> 2, sc = tid & 3;   // K staging: row 0..63, 16B chunk 0..3
  int vr = tid >> 3, vc = tid & 7;   // V staging: hd 0..31, 16B chunk 0..7
  const u16* kg = wk + tbase * 128 + h * 32;
  const u16* vg = wvt + ((size_t)(bp * 4 + h) * 32 + vr) * 512;
  const float cexp = 0.25500526f;    // log2(e)/sqrt(32)

  for (int t0 = 0; t0 < 512; t0 += 64) {
    __syncthreads();
    {
      uint4 ku = *(const uint4*)(kg + (size_t)(t0 + sr) * 128 + sc * 8);
      int swk = (sr >> 1) & 7;
      *(uint2*)(Ks + sr * 32 + (((sc * 2)     ^ swk) << 2)) = make_uint2(ku.x, ku.y);
      *(uint2*)(Ks + sr * 32 + (((sc * 2 + 1) ^ swk) << 2)) = make_uint2(ku.z, ku.w);
      uint4 vu = *(const uint4*)(vg + t0 + vc * 8);
      int swv = vr & 15;
      *(uint2*)(Vs + vr * 64 + (((vc * 2)     ^ swv) << 2)) = make_uint2(vu.x, vu.y);
      *(uint2*)(Vs + vr * 64 + (((vc * 2 + 1) ^ swv) << 2)) = make_uint2(vu.z, vu.w);
    }
    __syncthreads();
    // --- QK^T: S^T[k][q], k in tile (64), q in wave's 64 rows ---
    f32x4 S[4][4];
#pragma unroll
    for (int mt = 0; mt < 4; mt++) {
      int kr = mt * 16 + l15;
      const u16* kp = Ks + kr * 32;
      int swk = (kr >> 1) & 7;
      f16x4 a0 = __builtin_bit_cast(f16x4, *(const uint2*)(kp + ((l4       ^ swk) << 2)));
      f16x4 a1 = __builtin_bit_cast(f16x4, *(const uint2*)(kp + (((4 + l4) ^ swk) << 2)));
#pragma unroll
      for (int nt = 0; nt < 4; nt++) {
        f32x4 acc = {0.f, 0.f, 0.f, 0.f};
        acc = __builtin_amdgcn_mfma_f32_16x16x16f16(a0, __builtin_bit_cast(f16x4, qf[0][nt]), acc, 0, 0, 0);
        acc = __builtin_amdgcn_mfma_f32_16x16x16f16(a1, __builtin_bit_cast(f16x4, qf[1][nt]), acc, 0, 0, 0);
        S[mt][nt] = acc;
      }
    }
    // --- softmax (no max-sub) + PV, interleaved per k-slice ks ---
#pragma unroll
    for (int ks = 0; ks < 4; ks++) {
      f16x4 vf[2];
#pragma unroll
      for (int mt2 = 0; mt2 < 2; mt2++) {
        int hd = mt2 * 16 + l15;
        int g = ks * 4 + l4;
        vf[mt2] = __builtin_bit_cast(f16x4, *(const uint2*)(Vs + hd * 64 + ((g ^ l15) << 2)));
      }
#pragma unroll
      for (int nt = 0; nt < 4; nt++) {
        f32x4 s4 = S[ks][nt];
        float e0 = exp2f(s4[0] * cexp);
        float e1 = exp2f(s4[1] * cexp);
        float e2 = exp2f(s4[2] * cexp);
        float e3 = exp2f(s4[3] * cexp);
        lsum[nt] += (e0 + e1) + (e2 + e3);
        uint2 pf = make_uint2(pack2h(e0, e1), pack2h(e2, e3));
        f16x4 pb = __builtin_bit_cast(f16x4, pf);
#pragma unroll
        for (int mt2 = 0; mt2 < 2; mt2++)
          O[mt2][nt] = __builtin_amdgcn_mfma_f32_16x16x16f16(vf[mt2], pb, O[mt2][nt], 0, 0, 0);
      }
    }
  }
  // denominators: reduce across the 4 l4-groups
#pragma unroll
  for (int nt = 0; nt < 4; nt++) {
    float l2 = lsum[nt] + __shfl_xor(lsum[nt], 16);
    l2 += __shfl_xor(l2, 32);
    lsum[nt] = 1.f / l2;
  }
  // store att (overwrites this block's own q-rows / h-cols only)
#pragma unroll
  for (int mt2 = 0; mt2 < 2; mt2++)
#pragma unroll
    for (int nt = 0; nt < 4; nt++) {
      float r = lsum[nt];
      uint2 ov = make_uint2(pack2h(O[mt2][nt][0] * r, O[mt2][nt][1] * r),
                            pack2h(O[mt2][nt][2] * r, O[mt2][nt][3] * r));
      *(uint2*)(wq_att + (tbase + q0 + nt * 16 + l15) * 128 + h * 32 + mt2 * 16 + l4 * 4) = ov;
    }
}

// ---------------------------------------------------------------------------
// Output projection (att @ Wo^T + bo) * cm, scatter-add into out (=agg).
__global__ __launch_bounds__(256) void proj_k(
    const u16* __restrict__ watt, const u16* __restrict__ bp, const float* __restrict__ bo,
    const int* __restrict__ pidx, const float* __restrict__ cm, float* __restrict__ out) {
  __shared__ uint4 As[64 * 16];
  __shared__ int pis[64];
  __shared__ float cms[64];
  int tid = threadIdx.x;
  int t0 = blockIdx.x * 64;
  {
    int r = tid >> 2, qd = tid & 3;
    int T = t0 + r;
    int b = T / PS_;
    int ps = T - b * PS_;
    if (qd == 0) { pis[r] = b * N_ + pidx[ps]; cms[r] = cm[ps]; }
    const uint4* src = (const uint4*)(watt + (size_t)T * D_ + qd * 32);
#pragma unroll
    for (int c = 0; c < 4; c++) {
      int byteoff = (qd * 64 + c * 16) ^ ((r & 7) << 4);
      As[r * 16 + (byteoff >> 4)] = src[c];
    }
  }
  __syncthreads();
  int lane = tid & 63, wid = tid >> 6;
  int l15 = lane & 15, l4 = lane >> 4;
  int wm = wid & 1, wn = wid >> 1;
  uint2 bfrag[4][8];
  const uint2* bpp = (const uint2*)bp;
#pragma unroll
  for (int nt = 0; nt < 4; nt++) {
    int ntg = wn * 4 + nt;
#pragma unroll
    for (int ks = 0; ks < 8; ks++)
      bfrag[nt][ks] = bpp[(3 * 64 + ntg * 8 + ks) * 64 + lane];
  }
  f32x4 acc[2][4];
#pragma unroll
  for (int mt = 0; mt < 2; mt++)
#pragma unroll
    for (int nt = 0; nt < 4; nt++) {
      f32x4 z = {0.f, 0.f, 0.f, 0.f};
      acc[mt][nt] = z;
    }
  uint2 afr[2][8];
#pragma unroll
  for (int mt = 0; mt < 2; mt++) {
    int row = wm * 32 + mt * 16 + l15;
#pragma unroll
    for (int ks = 0; ks < 8; ks++) {
      int byteoff = (ks * 32 + (l4 << 3)) ^ ((row & 7) << 4);
      afr[mt][ks] = *(const uint2*)((const char*)As + row * 256 + byteoff);
    }
  }
#pragma unroll
  for (int ks = 0; ks < 8; ks++) {
#pragma unroll
    for (int mt = 0; mt < 2; mt++) {
      f16x4 a = __builtin_bit_cast(f16x4, afr[mt][ks]);
#pragma unroll
      for (int nt = 0; nt < 4; nt++) {
        f16x4 b = __builtin_bit_cast(f16x4, bfrag[nt][ks]);
        acc[mt][nt] = __builtin_amdgcn_mfma_f32_16x16x16f16(a, b, acc[mt][nt], 0, 0, 0);
      }
    }
  }
#pragma unroll
  for (int mt = 0; mt < 2; mt++) {
    int rl = wm * 32 + mt * 16 + (l4 << 2);
#pragma unroll
    for (int nt = 0; nt < 4; nt++) {
      int col = wn * 64 + nt * 16 + l15;
      float bov = bo[col];
#pragma unroll
      for (int i = 0; i < 4; i++) {
        float cmv = cms[rl + i];
        if (cmv != 0.f) {
          float val = (acc[mt][nt][i] + bov) * cmv;
          atomicAdd(out + (size_t)pis[rl + i] * D_ + col, val);
        }
      }
    }
  }
}

// ---------------------------------------------------------------------------
// h = x + agg/max(cnt,1); LayerNorm over D; in-place on out.
__global__ __launch_bounds__(256) void ln_k(
    const float* __restrict__ x, const float* __restrict__ cnt,
    const float* __restrict__ g, const float* __restrict__ bta, float* __restrict__ out) {
  int tid = threadIdx.x;
  int row = blockIdx.x * 8 + (tid >> 5);
  if (row >= B_ * N_) return;
  int l32 = tid & 31;
  int n = row % N_;
  float c = cnt[n];
  c = c > 1.f ? c : 1.f;
  float rc = 1.f / c;
  size_t off = (size_t)row * D_ + l32 * 4;
  float4 xa = *(const float4*)(x + off);
  float4 ag = *(const float4*)(out + off);
  float4 hv = make_float4(fmaf(ag.x, rc, xa.x), fmaf(ag.y, rc, xa.y),
                          fmaf(ag.z, rc, xa.z), fmaf(ag.w, rc, xa.w));
  float s = hv.x + hv.y + hv.z + hv.w;
  float s2 = hv.x * hv.x + hv.y * hv.y + hv.z * hv.z + hv.w * hv.w;
#pragma unroll
  for (int m = 16; m >= 1; m >>= 1) {
    s += __shfl_xor(s, m);
    s2 += __shfl_xor(s2, m);
  }
  float mu = s * 0.0078125f;
  float var = s2 * 0.0078125f - mu * mu;
  float rstd = rsqrtf(var + 1e-5f);
  float4 gv = *(const float4*)(g + l32 * 4);
  float4 bv = *(const float4*)(bta + l32 * 4);
  float4 ov = make_float4((hv.x - mu) * rstd * gv.x + bv.x,
                          (hv.y - mu) * rstd * gv.y + bv.y,
                          (hv.z - mu) * rstd * gv.z + bv.z,
                          (hv.w - mu) * rstd * gv.w + bv.w);
  *(float4*)(out + off) = ov;
}

// ---------------------------------------------------------------------------
extern "C" void kernel_launch(void* const* d_in, const int* in_sizes, int n_in,
                              void* d_out, int out_size, void* d_ws, size_t ws_size,
                              hipStream_t stream) {
  const float* x   = (const float*)d_in[0];
  const float* Wq  = (const float*)d_in[1];
  const float* bq  = (const float*)d_in[2];
  const float* Wk  = (const float*)d_in[3];
  const float* bk  = (const float*)d_in[4];
  const float* Wv  = (const float*)d_in[5];
  const float* bv  = (const float*)d_in[6];
  const float* Wo  = (const float*)d_in[7];
  const float* bo  = (const float*)d_in[8];
  const float* lng = (const float*)d_in[9];
  const float* lnb = (const float*)d_in[10];
  const int* pidx  = (const int*)d_in[11];
  const void* cmask = d_in[12];
  float* out = (float*)d_out;
  char* ws = (char*)d_ws;

  u16* wsq = (u16*)(ws + OFF_Q);
  u16* wsk = (u16*)(ws + OFF_K);
  u16* wsvt = (u16*)(ws + OFF_V);
  u16* wbp = (u16*)(ws + OFF_BP);
  float* wcnt = (float*)(ws + OFF_CNT);
  float* wcm  = (float*)(ws + OFF_CM);
  int* wflag  = (int*)(ws + OFF_FLAG);

  hipMemsetAsync(d_out, 0, (size_t)out_size * sizeof(float), stream);
  hipMemsetAsync(ws + OFF_CNT, 0, (OFF_FLAG + 4) - OFF_CNT, stream);

  probe_mask_k<<<1, 256, 0, stream>>>((const unsigned char*)cmask, wflag);
  mask_cnt_k<<<200, 256, 0, stream>>>(cmask, pidx, wflag, wcm, wcnt);
  pack_w_k<<<64, 256, 0, stream>>>(Wq, Wk, Wv, Wo, wbp);
  qkv_k<<<dim3(1600, 3), 256, 0, stream>>>(x, pidx, wbp, bq, bk, bv, wsq);
  attn_k<<<1600, 256, 0, stream>>>(wsq, wsk, wsvt);
  proj_k<<<1600, 256, 0, stream>>>(wsq, wbp, bo, pidx, wcm, out);
  ln_k<<<10241, 256, 0, stream>>>(x, wcnt, lng, lnb, out);
}

// Round 4
// 230.259 us; speedup vs baseline: 2.6381x; 1.1191x over previous
//
#include <hip/hip_runtime.h>
#include <hip/hip_bf16.h>
#include <hip/hip_fp16.h>

// Problem constants
#define B_ 2
#define N_ 40962
#define D_ 128
#define H_ 4
#define P_ 100
#define S_ 512
#define T_ 102400      // B*P*S tokens
#define PS_ 51200      // P*S

typedef unsigned short u16;
typedef unsigned int u32;
typedef _Float16 f16x4 __attribute__((ext_vector_type(4)));
typedef float f32x4 __attribute__((ext_vector_type(4)));

// Workspace byte offsets (total ~79.2 MB)
#define OFF_Q    0ull           // q fp16 [T][128]  (later reused as att)
#define OFF_K    26214400ull    // k fp16 [T][128]
#define OFF_V    52428800ull    // v fp16 V^T: [bp*4+h][32][512]
#define OFF_BP   78643200ull    // packed W frags: 4 mats x 4096 lane-frags x 8B
#define OFF_CNT  78774272ull    // float cnt[N]
#define OFF_CM   78938120ull    // float cm[P*S]
#define OFF_FLAG 79142920ull    // int dtype flag for core_mask

__device__ __forceinline__ u32 pack2h(float a, float b) {
  __half2 h = __floats2half2_rn(a, b);
  return __builtin_bit_cast(u32, h);
}

// ---------------------------------------------------------------------------
// Probe core_mask storage format (bool8 / int32 / float32) — see round 0.
__global__ void probe_mask_k(const unsigned char* __restrict__ mb, int* __restrict__ flag) {
  int f = 0;
  for (int i = threadIdx.x; i < PS_; i += 256) {
    unsigned char v = mb[i];
    if (v) {
      int m4 = i & 3;
      if (m4 == 1) f |= 1;
      else if (m4 == 3) f |= 2;
    }
  }
  if (f) atomicOr(flag, f);
}

// cm[i] = mask as float; cnt[n] += cm
__global__ void mask_cnt_k(const void* __restrict__ mask, const int* __restrict__ pidx,
                           const int* __restrict__ flag, float* __restrict__ cm,
                           float* __restrict__ cnt) {
  int i = blockIdx.x * 256 + threadIdx.x;
  int fl = *flag;
  bool on;
  if (fl & 1)      on = ((const unsigned char*)mask)[i] != 0;
  else if (fl & 2) on = ((const float*)mask)[i] != 0.f;
  else             on = ((const int*)mask)[i] != 0;
  cm[i] = on ? 1.f : 0.f;
  if (on) atomicAdd(&cnt[pidx[i]], 1.f);
}

// ---------------------------------------------------------------------------
// Pack Wq/Wk/Wv/Wo into MFMA B-fragment order (fp16). See round 0.
__global__ void pack_w_k(const float* __restrict__ Wq, const float* __restrict__ Wk,
                         const float* __restrict__ Wv, const float* __restrict__ Wo,
                         u16* __restrict__ bp) {
  int gi = blockIdx.x * 256 + threadIdx.x;   // < 16384
  int m = gi >> 12;
  int r = gi & 4095;
  int fi = r >> 6;         // nt*8 + ks
  int l = r & 63;
  int nt = fi >> 3, ks = fi & 7;
  const float* W = (m == 0) ? Wq : (m == 1) ? Wk : (m == 2) ? Wv : Wo;
  int n = nt * 16 + (l & 15);
  int k0 = ks * 16 + ((l >> 4) << 2);
  float4 w = *(const float4*)(W + n * 128 + k0);
  *(uint2*)(bp + (size_t)gi * 4) = make_uint2(pack2h(w.x, w.y), pack2h(w.z, w.w));
}

// ---------------------------------------------------------------------------
// Gather px rows + QKV projection GEMM. mat 0/1 -> [T][128]; mat 2 -> V^T
// layout [bp*4+h][hd=32][s=512] so attention's PV A-frag is a contiguous read.
__global__ __launch_bounds__(256) void qkv_k(
    const float* __restrict__ x, const int* __restrict__ pidx,
    const u16* __restrict__ bp,
    const float* __restrict__ bq, const float* __restrict__ bk, const float* __restrict__ bv,
    u16* __restrict__ qkv) {
  __shared__ uint4 As[64 * 16];   // 64 rows x 128 fp16, XOR-swizzled
  int tid = threadIdx.x;
  int mat = blockIdx.y;
  int t0 = blockIdx.x * 64;
  {
    int r = tid >> 2, qd = tid & 3;
    int T = t0 + r;
    int b = T / PS_;
    int ps = T - b * PS_;
    int pi = pidx[ps];
    const float4* src = (const float4*)(x + ((size_t)b * N_ + pi) * D_ + qd * 32);
    u32 us[16];
#pragma unroll
    for (int j = 0; j < 8; j++) {
      float4 f = src[j];
      us[2 * j]     = pack2h(f.x, f.y);
      us[2 * j + 1] = pack2h(f.z, f.w);
    }
#pragma unroll
    for (int c = 0; c < 4; c++) {
      int byteoff = (qd * 64 + c * 16) ^ ((r & 7) << 4);
      As[r * 16 + (byteoff >> 4)] = make_uint4(us[4 * c], us[4 * c + 1], us[4 * c + 2], us[4 * c + 3]);
    }
  }
  __syncthreads();
  int lane = tid & 63, wid = tid >> 6;
  int l15 = lane & 15, l4 = lane >> 4;
  int wm = wid & 1, wn = wid >> 1;
  uint2 bfrag[4][8];
  const uint2* bpp = (const uint2*)bp;
#pragma unroll
  for (int nt = 0; nt < 4; nt++) {
    int ntg = wn * 4 + nt;
#pragma unroll
    for (int ks = 0; ks < 8; ks++)
      bfrag[nt][ks] = bpp[(mat * 64 + ntg * 8 + ks) * 64 + lane];
  }
  const float* bias = (mat == 0) ? bq : (mat == 1) ? bk : bv;
  f32x4 acc[2][4];
#pragma unroll
  for (int nt = 0; nt < 4; nt++) {
    float bvv = bias[wn * 64 + nt * 16 + l15];
#pragma unroll
    for (int mt = 0; mt < 2; mt++) {
      f32x4 z = {bvv, bvv, bvv, bvv};
      acc[mt][nt] = z;
    }
  }
  uint2 afr[2][8];
#pragma unroll
  for (int mt = 0; mt < 2; mt++) {
    int row = wm * 32 + mt * 16 + l15;
#pragma unroll
    for (int ks = 0; ks < 8; ks++) {
      int byteoff = (ks * 32 + (l4 << 3)) ^ ((row & 7) << 4);
      afr[mt][ks] = *(const uint2*)((const char*)As + row * 256 + byteoff);
    }
  }
#pragma unroll
  for (int ks = 0; ks < 8; ks++) {
#pragma unroll
    for (int mt = 0; mt < 2; mt++) {
      f16x4 a = __builtin_bit_cast(f16x4, afr[mt][ks]);
#pragma unroll
      for (int nt = 0; nt < 4; nt++) {
        f16x4 b = __builtin_bit_cast(f16x4, bfrag[nt][ks]);
        acc[mt][nt] = __builtin_amdgcn_mfma_f32_16x16x16f16(a, b, acc[mt][nt], 0, 0, 0);
      }
    }
  }
  if (mat == 2) {
    u16* vt = qkv + (size_t)2 * T_ * D_;
#pragma unroll
    for (int mt = 0; mt < 2; mt++) {
      int rbase = t0 + wm * 32 + mt * 16 + (l4 << 2);
      int bpi = rbase >> 9;        // b*P + p (same for all 4 i)
      int s = rbase & 511;
#pragma unroll
      for (int nt = 0; nt < 4; nt++) {
        int col = wn * 64 + nt * 16 + l15;
        uint2 pv = make_uint2(pack2h(acc[mt][nt][0], acc[mt][nt][1]),
                              pack2h(acc[mt][nt][2], acc[mt][nt][3]));
        *(uint2*)(vt + ((size_t)(bpi * 4 + (col >> 5)) * 32 + (col & 31)) * 512 + s) = pv;
      }
    }
  } else {
    u16* outp = qkv + (size_t)mat * T_ * D_;
#pragma unroll
    for (int mt = 0; mt < 2; mt++) {
      int rbase = t0 + wm * 32 + mt * 16 + (l4 << 2);
#pragma unroll
      for (int nt = 0; nt < 4; nt++) {
        int col = wn * 64 + nt * 16 + l15;
#pragma unroll
        for (int i = 0; i < 4; i++) {
          __half hv = __float2half(acc[mt][nt][i]);
          outp[(size_t)(rbase + i) * D_ + col] = __builtin_bit_cast(u16, hv);
        }
      }
    }
  }
}

// ---------------------------------------------------------------------------
// MFMA flash-attention, swapped operands, lean softmax:
//  - scale log2(e)/sqrt(32) folded into Q frags (v_pk_mul_f16, once)
//  - raw v_exp_f32 via __builtin_amdgcn_exp2f (1 instr/score)
//  - row-sums via ones-A MFMA (LS accumulator): no scalar adds, no shuffles;
//    denominator computed from the same f16-quantized P used in PV.
//  - per k-slice (mt) structure keeps S live range at 4 f32.
__global__ __launch_bounds__(256) void attn_k(
    u16* wq_att, const u16* __restrict__ wk, const u16* __restrict__ wvt) {
  __shared__ __align__(16) u16 Ks[64 * 32];   // [k-row][32 hd], granule-swizzled
  __shared__ __align__(16) u16 Vs[32 * 64];   // [hd][64 k], granule-swizzled
  int tid = threadIdx.x;
  int bid = blockIdx.x;
  int bp = bid >> 3;
  int h = (bid >> 1) & 3;
  int qh = bid & 1;
  int lane = tid & 63, w = tid >> 6;
  int l15 = lane & 15, l4 = lane >> 4;
  size_t tbase = (size_t)bp * 512;
  int q0 = qh * 256 + w * 64;
  // Q B-frags [ks][nt], pre-scaled by log2(e)/sqrt(32)
  uint2 qf[2][4];
  {
    const u16* qbase = wq_att + (tbase + q0) * 128 + h * 32;
    const __half2 sc2 = __floats2half2_rn(0.25500527f, 0.25500527f);
#pragma unroll
    for (int nt = 0; nt < 4; nt++)
#pragma unroll
      for (int ks = 0; ks < 2; ks++) {
        uint2 u = *(const uint2*)(qbase + (size_t)(nt * 16 + l15) * 128 + ks * 16 + l4 * 4);
        __half2 a = __builtin_bit_cast(__half2, u.x);
        __half2 b = __builtin_bit_cast(__half2, u.y);
        a = __hmul2(a, sc2);
        b = __hmul2(b, sc2);
        qf[ks][nt] = make_uint2(__builtin_bit_cast(u32, a), __builtin_bit_cast(u32, b));
      }
  }
  f32x4 O[2][4];
  f32x4 LS[4];
#pragma unroll
  for (int a = 0; a < 4; a++) {
    O[0][a] = (f32x4){0.f, 0.f, 0.f, 0.f};
    O[1][a] = (f32x4){0.f, 0.f, 0.f, 0.f};
    LS[a] = (f32x4){0.f, 0.f, 0.f, 0.f};
  }
  const f16x4 ones = {(_Float16)1.f, (_Float16)1.f, (_Float16)1.f, (_Float16)1.f};
  int sr = tid >> 2, sc = tid & 3;   // K staging: row 0..63, 16B chunk 0..3
  int vr = tid >> 3, vc = tid & 7;   // V staging: hd 0..31, 16B chunk 0..7
  const u16* kg = wk + tbase * 128 + h * 32;
  const u16* vg = wvt + ((size_t)(bp * 4 + h) * 32 + vr) * 512;

  for (int t0 = 0; t0 < 512; t0 += 64) {
    __syncthreads();
    {
      uint4 ku = *(const uint4*)(kg + (size_t)(t0 + sr) * 128 + sc * 8);
      int swk = (sr >> 1) & 7;
      *(uint2*)(Ks + sr * 32 + (((sc * 2)     ^ swk) << 2)) = make_uint2(ku.x, ku.y);
      *(uint2*)(Ks + sr * 32 + (((sc * 2 + 1) ^ swk) << 2)) = make_uint2(ku.z, ku.w);
      uint4 vu = *(const uint4*)(vg + t0 + vc * 8);
      int swv = vr & 15;
      *(uint2*)(Vs + vr * 64 + (((vc * 2)     ^ swv) << 2)) = make_uint2(vu.x, vu.y);
      *(uint2*)(Vs + vr * 64 + (((vc * 2 + 1) ^ swv) << 2)) = make_uint2(vu.z, vu.w);
    }
    __syncthreads();
#pragma unroll
    for (int mt = 0; mt < 4; mt++) {
      // K A-frags for this 16-k slice
      int kr = mt * 16 + l15;
      const u16* kp = Ks + kr * 32;
      int swk = (kr >> 1) & 7;
      f16x4 a0 = __builtin_bit_cast(f16x4, *(const uint2*)(kp + ((l4       ^ swk) << 2)));
      f16x4 a1 = __builtin_bit_cast(f16x4, *(const uint2*)(kp + (((4 + l4) ^ swk) << 2)));
      // V^T A-frags for this 16-k slice
      int g = mt * 4 + l4;
      f16x4 vf0 = __builtin_bit_cast(f16x4, *(const uint2*)(Vs + l15 * 64        + ((g ^ l15) << 2)));
      f16x4 vf1 = __builtin_bit_cast(f16x4, *(const uint2*)(Vs + (16 + l15) * 64 + ((g ^ l15) << 2)));
#pragma unroll
      for (int nt = 0; nt < 4; nt++) {
        f32x4 s = {0.f, 0.f, 0.f, 0.f};
        s = __builtin_amdgcn_mfma_f32_16x16x16f16(a0, __builtin_bit_cast(f16x4, qf[0][nt]), s, 0, 0, 0);
        s = __builtin_amdgcn_mfma_f32_16x16x16f16(a1, __builtin_bit_cast(f16x4, qf[1][nt]), s, 0, 0, 0);
        float e0 = __builtin_amdgcn_exp2f(s[0]);
        float e1 = __builtin_amdgcn_exp2f(s[1]);
        float e2 = __builtin_amdgcn_exp2f(s[2]);
        float e3 = __builtin_amdgcn_exp2f(s[3]);
        u32 p01 = __builtin_bit_cast(u32, __builtin_amdgcn_cvt_pkrtz(e0, e1));
        u32 p23 = __builtin_bit_cast(u32, __builtin_amdgcn_cvt_pkrtz(e2, e3));
        uint2 pu = make_uint2(p01, p23);
        f16x4 pb = __builtin_bit_cast(f16x4, pu);
        LS[nt]   = __builtin_amdgcn_mfma_f32_16x16x16f16(ones, pb, LS[nt], 0, 0, 0);
        O[0][nt] = __builtin_amdgcn_mfma_f32_16x16x16f16(vf0, pb, O[0][nt], 0, 0, 0);
        O[1][nt] = __builtin_amdgcn_mfma_f32_16x16x16f16(vf1, pb, O[1][nt], 0, 0, 0);
      }
    }
  }
  // store att (overwrites this block's own q-rows / h-cols only)
#pragma unroll
  for (int nt = 0; nt < 4; nt++) {
    float r = 1.f / LS[nt][0];
#pragma unroll
    for (int mt2 = 0; mt2 < 2; mt2++) {
      uint2 ov = make_uint2(pack2h(O[mt2][nt][0] * r, O[mt2][nt][1] * r),
                            pack2h(O[mt2][nt][2] * r, O[mt2][nt][3] * r));
      *(uint2*)(wq_att + (tbase + q0 + nt * 16 + l15) * 128 + h * 32 + mt2 * 16 + l4 * 4) = ov;
    }
  }
}

// ---------------------------------------------------------------------------
// Output projection (att @ Wo^T + bo) * cm, scatter-add into out (=agg).
__global__ __launch_bounds__(256) void proj_k(
    const u16* __restrict__ watt, const u16* __restrict__ bp, const float* __restrict__ bo,
    const int* __restrict__ pidx, const float* __restrict__ cm, float* __restrict__ out) {
  __shared__ uint4 As[64 * 16];
  __shared__ int pis[64];
  __shared__ float cms[64];
  int tid = threadIdx.x;
  int t0 = blockIdx.x * 64;
  {
    int r = tid >> 2, qd = tid & 3;
    int T = t0 + r;
    int b = T / PS_;
    int ps = T - b * PS_;
    if (qd == 0) { pis[r] = b * N_ + pidx[ps]; cms[r] = cm[ps]; }
    const uint4* src = (const uint4*)(watt + (size_t)T * D_ + qd * 32);
#pragma unroll
    for (int c = 0; c < 4; c++) {
      int byteoff = (qd * 64 + c * 16) ^ ((r & 7) << 4);
      As[r * 16 + (byteoff >> 4)] = src[c];
    }
  }
  __syncthreads();
  int lane = tid & 63, wid = tid >> 6;
  int l15 = lane & 15, l4 = lane >> 4;
  int wm = wid & 1, wn = wid >> 1;
  uint2 bfrag[4][8];
  const uint2* bpp = (const uint2*)bp;
#pragma unroll
  for (int nt = 0; nt < 4; nt++) {
    int ntg = wn * 4 + nt;
#pragma unroll
    for (int ks = 0; ks < 8; ks++)
      bfrag[nt][ks] = bpp[(3 * 64 + ntg * 8 + ks) * 64 + lane];
  }
  f32x4 acc[2][4];
#pragma unroll
  for (int mt = 0; mt < 2; mt++)
#pragma unroll
    for (int nt = 0; nt < 4; nt++) {
      f32x4 z = {0.f, 0.f, 0.f, 0.f};
      acc[mt][nt] = z;
    }
  uint2 afr[2][8];
#pragma unroll
  for (int mt = 0; mt < 2; mt++) {
    int row = wm * 32 + mt * 16 + l15;
#pragma unroll
    for (int ks = 0; ks < 8; ks++) {
      int byteoff = (ks * 32 + (l4 << 3)) ^ ((row & 7) << 4);
      afr[mt][ks] = *(const uint2*)((const char*)As + row * 256 + byteoff);
    }
  }
#pragma unroll
  for (int ks = 0; ks < 8; ks++) {
#pragma unroll
    for (int mt = 0; mt < 2; mt++) {
      f16x4 a = __builtin_bit_cast(f16x4, afr[mt][ks]);
#pragma unroll
      for (int nt = 0; nt < 4; nt++) {
        f16x4 b = __builtin_bit_cast(f16x4, bfrag[nt][ks]);
        acc[mt][nt] = __builtin_amdgcn_mfma_f32_16x16x16f16(a, b, acc[mt][nt], 0, 0, 0);
      }
    }
  }
#pragma unroll
  for (int mt = 0; mt < 2; mt++) {
    int rl = wm * 32 + mt * 16 + (l4 << 2);
#pragma unroll
    for (int nt = 0; nt < 4; nt++) {
      int col = wn * 64 + nt * 16 + l15;
      float bov = bo[col];
#pragma unroll
      for (int i = 0; i < 4; i++) {
        float cmv = cms[rl + i];
        if (cmv != 0.f) {
          float val = (acc[mt][nt][i] + bov) * cmv;
          atomicAdd(out + (size_t)pis[rl + i] * D_ + col, val);
        }
      }
    }
  }
}

// ---------------------------------------------------------------------------
// h = x + agg/max(cnt,1); LayerNorm over D; in-place on out.
__global__ __launch_bounds__(256) void ln_k(
    const float* __restrict__ x, const float* __restrict__ cnt,
    const float* __restrict__ g, const float* __restrict__ bta, float* __restrict__ out) {
  int tid = threadIdx.x;
  int row = blockIdx.x * 8 + (tid >> 5);
  if (row >= B_ * N_) return;
  int l32 = tid & 31;
  int n = row % N_;
  float c = cnt[n];
  c = c > 1.f ? c : 1.f;
  float rc = 1.f / c;
  size_t off = (size_t)row * D_ + l32 * 4;
  float4 xa = *(const float4*)(x + off);
  float4 ag = *(const float4*)(out + off);
  float4 hv = make_float4(fmaf(ag.x, rc, xa.x), fmaf(ag.y, rc, xa.y),
                          fmaf(ag.z, rc, xa.z), fmaf(ag.w, rc, xa.w));
  float s = hv.x + hv.y + hv.z + hv.w;
  float s2 = hv.x * hv.x + hv.y * hv.y + hv.z * hv.z + hv.w * hv.w;
#pragma unroll
  for (int m = 16; m >= 1; m >>= 1) {
    s += __shfl_xor(s, m);
    s2 += __shfl_xor(s2, m);
  }
  float mu = s * 0.0078125f;
  float var = s2 * 0.0078125f - mu * mu;
  float rstd = rsqrtf(var + 1e-5f);
  float4 gv = *(const float4*)(g + l32 * 4);
  float4 bv = *(const float4*)(bta + l32 * 4);
  float4 ov = make_float4((hv.x - mu) * rstd * gv.x + bv.x,
                          (hv.y - mu) * rstd * gv.y + bv.y,
                          (hv.z - mu) * rstd * gv.z + bv.z,
                          (hv.w - mu) * rstd * gv.w + bv.w);
  *(float4*)(out + off) = ov;
}

// ---------------------------------------------------------------------------
extern "C" void kernel_launch(void* const* d_in, const int* in_sizes, int n_in,
                              void* d_out, int out_size, void* d_ws, size_t ws_size,
                              hipStream_t stream) {
  const float* x   = (const float*)d_in[0];
  const float* Wq  = (const float*)d_in[1];
  const float* bq  = (const float*)d_in[2];
  const float* Wk  = (const float*)d_in[3];
  const float* bk  = (const float*)d_in[4];
  const float* Wv  = (const float*)d_in[5];
  const float* bv  = (const float*)d_in[6];
  const float* Wo  = (const float*)d_in[7];
  const float* bo  = (const float*)d_in[8];
  const float* lng = (const float*)d_in[9];
  const float* lnb = (const float*)d_in[10];
  const int* pidx  = (const int*)d_in[11];
  const void* cmask = d_in[12];
  float* out = (float*)d_out;
  char* ws = (char*)d_ws;

  u16* wsq = (u16*)(ws + OFF_Q);
  u16* wsk = (u16*)(ws + OFF_K);
  u16* wsvt = (u16*)(ws + OFF_V);
  u16* wbp = (u16*)(ws + OFF_BP);
  float* wcnt = (float*)(ws + OFF_CNT);
  float* wcm  = (float*)(ws + OFF_CM);
  int* wflag  = (int*)(ws + OFF_FLAG);

  hipMemsetAsync(d_out, 0, (size_t)out_size * sizeof(float), stream);
  hipMemsetAsync(ws + OFF_CNT, 0, (OFF_FLAG + 4) - OFF_CNT, stream);

  probe_mask_k<<<1, 256, 0, stream>>>((const unsigned char*)cmask, wflag);
  mask_cnt_k<<<200, 256, 0, stream>>>(cmask, pidx, wflag, wcm, wcnt);
  pack_w_k<<<64, 256, 0, stream>>>(Wq, Wk, Wv, Wo, wbp);
  qkv_k<<<dim3(1600, 3), 256, 0, stream>>>(x, pidx, wbp, bq, bk, bv, wsq);
  attn_k<<<1600, 256, 0, stream>>>(wsq, wsk, wsvt);
  proj_k<<<1600, 256, 0, stream>>>(wsq, wbp, bo, pidx, wcm, out);
  ln_k<<<10241, 256, 0, stream>>>(x, wcnt, lng, lnb, out);
}

// Round 5
// 208.807 us; speedup vs baseline: 2.9091x; 1.1027x over previous
//
#include <hip/hip_runtime.h>
#include <hip/hip_bf16.h>
#include <hip/hip_fp16.h>

// Problem constants
#define B_ 2
#define N_ 40962
#define D_ 128
#define H_ 4
#define P_ 100
#define S_ 512
#define T_ 102400      // B*P*S tokens
#define PS_ 51200      // P*S

typedef unsigned short u16;
typedef unsigned int u32;
typedef _Float16 f16x4 __attribute__((ext_vector_type(4)));
typedef _Float16 f16x8 __attribute__((ext_vector_type(8)));
typedef float f32x4 __attribute__((ext_vector_type(4)));

// Workspace byte offsets (total ~79.2 MB)
#define OFF_Q    0ull           // q fp16 [T][128]  (later reused as att)
#define OFF_K    26214400ull    // k fp16 [T][128]
#define OFF_V    52428800ull    // v fp16 V^T: [bp*4+h][32][512]
#define OFF_BP   78643200ull    // packed W frags: 4 mats x 4096 lane-frags x 8B
#define OFF_CNT  78774272ull    // float cnt[N]
#define OFF_CM   78938120ull    // float cm[P*S]
#define OFF_FLAG 79142920ull    // int dtype flag for core_mask

__device__ __forceinline__ u32 pack2h(float a, float b) {
  __half2 h = __floats2half2_rn(a, b);
  return __builtin_bit_cast(u32, h);
}

// 16x16x32 f16 MFMA; x32 frag = concat of two x16 half-frags (k 0..15, 16..31).
// Fallback (two x16 ops) is exactly equivalent under that layout.
__device__ __forceinline__ f32x4 mfma32(f16x8 a, f16x8 b, f32x4 c) {
#if __has_builtin(__builtin_amdgcn_mfma_f32_16x16x32_f16)
  return __builtin_amdgcn_mfma_f32_16x16x32_f16(a, b, c, 0, 0, 0);
#else
  f16x4 alo = {a[0], a[1], a[2], a[3]}, ahi = {a[4], a[5], a[6], a[7]};
  f16x4 blo = {b[0], b[1], b[2], b[3]}, bhi = {b[4], b[5], b[6], b[7]};
  c = __builtin_amdgcn_mfma_f32_16x16x16f16(alo, blo, c, 0, 0, 0);
  return __builtin_amdgcn_mfma_f32_16x16x16f16(ahi, bhi, c, 0, 0, 0);
#endif
}

// ---------------------------------------------------------------------------
// Probe core_mask storage format (bool8 / int32 / float32) — see round 0.
__global__ void probe_mask_k(const unsigned char* __restrict__ mb, int* __restrict__ flag) {
  int f = 0;
  for (int i = threadIdx.x; i < PS_; i += 256) {
    unsigned char v = mb[i];
    if (v) {
      int m4 = i & 3;
      if (m4 == 1) f |= 1;
      else if (m4 == 3) f |= 2;
    }
  }
  if (f) atomicOr(flag, f);
}

// cm[i] = mask as float; cnt[n] += cm
__global__ void mask_cnt_k(const void* __restrict__ mask, const int* __restrict__ pidx,
                           const int* __restrict__ flag, float* __restrict__ cm,
                           float* __restrict__ cnt) {
  int i = blockIdx.x * 256 + threadIdx.x;
  int fl = *flag;
  bool on;
  if (fl & 1)      on = ((const unsigned char*)mask)[i] != 0;
  else if (fl & 2) on = ((const float*)mask)[i] != 0.f;
  else             on = ((const int*)mask)[i] != 0;
  cm[i] = on ? 1.f : 0.f;
  if (on) atomicAdd(&cnt[pidx[i]], 1.f);
}

// ---------------------------------------------------------------------------
// Pack Wq/Wk/Wv/Wo into MFMA B-fragment order (fp16). See round 0.
__global__ void pack_w_k(const float* __restrict__ Wq, const float* __restrict__ Wk,
                         const float* __restrict__ Wv, const float* __restrict__ Wo,
                         u16* __restrict__ bp) {
  int gi = blockIdx.x * 256 + threadIdx.x;   // < 16384
  int m = gi >> 12;
  int r = gi & 4095;
  int fi = r >> 6;         // nt*8 + ks
  int l = r & 63;
  int nt = fi >> 3, ks = fi & 7;
  const float* W = (m == 0) ? Wq : (m == 1) ? Wk : (m == 2) ? Wv : Wo;
  int n = nt * 16 + (l & 15);
  int k0 = ks * 16 + ((l >> 4) << 2);
  float4 w = *(const float4*)(W + n * 128 + k0);
  *(uint2*)(bp + (size_t)gi * 4) = make_uint2(pack2h(w.x, w.y), pack2h(w.z, w.w));
}

// ---------------------------------------------------------------------------
// Gather px rows once + ALL THREE projections (q, k, v). A-tile staged once,
// afr register fragments reused across mats; bfrag reloaded per mat (L2-hot).
// mat 0/1 -> [T][128]; mat 2 -> V^T layout [bp*4+h][hd=32][s=512].
__global__ __launch_bounds__(256) void qkv_k(
    const float* __restrict__ x, const int* __restrict__ pidx,
    const u16* __restrict__ bp,
    const float* __restrict__ bq, const float* __restrict__ bk, const float* __restrict__ bv,
    u16* __restrict__ qkv) {
  __shared__ uint4 As[64 * 16];   // 64 rows x 128 fp16, XOR-swizzled
  int tid = threadIdx.x;
  int t0 = blockIdx.x * 64;
  {
    int r = tid >> 2, qd = tid & 3;
    int T = t0 + r;
    int b = T / PS_;
    int ps = T - b * PS_;
    int pi = pidx[ps];
    const float4* src = (const float4*)(x + ((size_t)b * N_ + pi) * D_ + qd * 32);
    u32 us[16];
#pragma unroll
    for (int j = 0; j < 8; j++) {
      float4 f = src[j];
      us[2 * j]     = pack2h(f.x, f.y);
      us[2 * j + 1] = pack2h(f.z, f.w);
    }
#pragma unroll
    for (int c = 0; c < 4; c++) {
      int byteoff = (qd * 64 + c * 16) ^ ((r & 7) << 4);
      As[r * 16 + (byteoff >> 4)] = make_uint4(us[4 * c], us[4 * c + 1], us[4 * c + 2], us[4 * c + 3]);
    }
  }
  __syncthreads();
  int lane = tid & 63, wid = tid >> 6;
  int l15 = lane & 15, l4 = lane >> 4;
  int wm = wid & 1, wn = wid >> 1;
  uint2 afr[2][8];
#pragma unroll
  for (int mt = 0; mt < 2; mt++) {
    int row = wm * 32 + mt * 16 + l15;
#pragma unroll
    for (int ks = 0; ks < 8; ks++) {
      int byteoff = (ks * 32 + (l4 << 3)) ^ ((row & 7) << 4);
      afr[mt][ks] = *(const uint2*)((const char*)As + row * 256 + byteoff);
    }
  }
  const uint2* bpp = (const uint2*)bp;
#pragma unroll 1
  for (int mat = 0; mat < 3; mat++) {
    uint2 bfrag[4][8];
#pragma unroll
    for (int nt = 0; nt < 4; nt++) {
      int ntg = wn * 4 + nt;
#pragma unroll
      for (int ks = 0; ks < 8; ks++)
        bfrag[nt][ks] = bpp[(mat * 64 + ntg * 8 + ks) * 64 + lane];
    }
    const float* bias = (mat == 0) ? bq : (mat == 1) ? bk : bv;
    f32x4 acc[2][4];
#pragma unroll
    for (int nt = 0; nt < 4; nt++) {
      float bvv = bias[wn * 64 + nt * 16 + l15];
#pragma unroll
      for (int mt = 0; mt < 2; mt++) {
        f32x4 z = {bvv, bvv, bvv, bvv};
        acc[mt][nt] = z;
      }
    }
#pragma unroll
    for (int ks = 0; ks < 8; ks++) {
#pragma unroll
      for (int mt = 0; mt < 2; mt++) {
        f16x4 a = __builtin_bit_cast(f16x4, afr[mt][ks]);
#pragma unroll
        for (int nt = 0; nt < 4; nt++) {
          f16x4 b = __builtin_bit_cast(f16x4, bfrag[nt][ks]);
          acc[mt][nt] = __builtin_amdgcn_mfma_f32_16x16x16f16(a, b, acc[mt][nt], 0, 0, 0);
        }
      }
    }
    if (mat == 2) {
      u16* vt = qkv + (size_t)2 * T_ * D_;
#pragma unroll
      for (int mt = 0; mt < 2; mt++) {
        int rbase = t0 + wm * 32 + mt * 16 + (l4 << 2);
        int bpi = rbase >> 9;        // b*P + p (same for all 4 i)
        int s = rbase & 511;
#pragma unroll
        for (int nt = 0; nt < 4; nt++) {
          int col = wn * 64 + nt * 16 + l15;
          uint2 pv = make_uint2(pack2h(acc[mt][nt][0], acc[mt][nt][1]),
                                pack2h(acc[mt][nt][2], acc[mt][nt][3]));
          *(uint2*)(vt + ((size_t)(bpi * 4 + (col >> 5)) * 32 + (col & 31)) * 512 + s) = pv;
        }
      }
    } else {
      u16* outp = qkv + (size_t)mat * T_ * D_;
#pragma unroll
      for (int mt = 0; mt < 2; mt++) {
        int rbase = t0 + wm * 32 + mt * 16 + (l4 << 2);
#pragma unroll
        for (int nt = 0; nt < 4; nt++) {
          int col = wn * 64 + nt * 16 + l15;
#pragma unroll
          for (int i = 0; i < 4; i++) {
            __half hv = __float2half(acc[mt][nt][i]);
            outp[(size_t)(rbase + i) * D_ + col] = __builtin_bit_cast(u16, hv);
          }
        }
      }
    }
  }
}

// ---------------------------------------------------------------------------
// MFMA flash-attention, swapped operands, 16x16x32 MFMA (x32 frag = concat of
// two verified x16 halves). One block = (bp, h), 512 threads / 8 waves; each
// wave owns 64 q-rows, so K/V tiles are staged (and fetched) ONCE per block.
__global__ __launch_bounds__(512) void attn_k(
    u16* wq_att, const u16* __restrict__ wk, const u16* __restrict__ wvt) {
  __shared__ __align__(16) u16 Ks[64 * 32];   // [k-row][32 hd], granule-swizzled
  __shared__ __align__(16) u16 Vs[32 * 64];   // [hd][64 k], granule-swizzled
  int tid = threadIdx.x;
  int bid = blockIdx.x;
  int h = bid & 3;
  int bp = bid >> 2;
  int lane = tid & 63, w = tid >> 6;
  int l15 = lane & 15, l4 = lane >> 4;
  size_t tbase = (size_t)bp * 512;
  int q0 = w * 64;
  // Q B-frags (x32: elems 0-3 = hd 4*l4..+3, elems 4-7 = hd 16+4*l4..+3),
  // pre-scaled by log2(e)/sqrt(32).
  uint4 qf8[4];
  {
    const u16* qbase = wq_att + (tbase + q0) * 128 + h * 32;
    const __half2 sc2 = __floats2half2_rn(0.25500527f, 0.25500527f);
#pragma unroll
    for (int nt = 0; nt < 4; nt++) {
      const u16* qr = qbase + (size_t)(nt * 16 + l15) * 128 + l4 * 4;
      uint2 u0 = *(const uint2*)(qr);
      uint2 u1 = *(const uint2*)(qr + 16);
      u32 w0 = __builtin_bit_cast(u32, __hmul2(__builtin_bit_cast(__half2, u0.x), sc2));
      u32 w1 = __builtin_bit_cast(u32, __hmul2(__builtin_bit_cast(__half2, u0.y), sc2));
      u32 w2 = __builtin_bit_cast(u32, __hmul2(__builtin_bit_cast(__half2, u1.x), sc2));
      u32 w3 = __builtin_bit_cast(u32, __hmul2(__builtin_bit_cast(__half2, u1.y), sc2));
      qf8[nt] = make_uint4(w0, w1, w2, w3);
    }
  }
  f32x4 O[2][4];
  f32x4 LS[4];
#pragma unroll
  for (int a = 0; a < 4; a++) {
    O[0][a] = (f32x4){0.f, 0.f, 0.f, 0.f};
    O[1][a] = (f32x4){0.f, 0.f, 0.f, 0.f};
    LS[a] = (f32x4){0.f, 0.f, 0.f, 0.f};
  }
  const f16x8 ones8 = {(_Float16)1.f, (_Float16)1.f, (_Float16)1.f, (_Float16)1.f,
                       (_Float16)1.f, (_Float16)1.f, (_Float16)1.f, (_Float16)1.f};
  int st = tid & 255;
  int sr = st >> 2, sc = tid & 3;    // K staging (tid<256): row 0..63, 16B chunk
  int vr = st >> 3, vc = tid & 7;    // V staging (tid>=256): hd 0..31, 16B chunk
  const u16* kg = wk + tbase * 128 + h * 32;
  const u16* vg = wvt + ((size_t)(bp * 4 + h) * 32 + vr) * 512;

  for (int t0 = 0; t0 < 512; t0 += 64) {
    __syncthreads();
    if (tid < 256) {
      uint4 ku = *(const uint4*)(kg + (size_t)(t0 + sr) * 128 + sc * 8);
      int swk = (sr >> 1) & 7;
      *(uint2*)(Ks + sr * 32 + (((sc * 2)     ^ swk) << 2)) = make_uint2(ku.x, ku.y);
      *(uint2*)(Ks + sr * 32 + (((sc * 2 + 1) ^ swk) << 2)) = make_uint2(ku.z, ku.w);
    } else {
      uint4 vu = *(const uint4*)(vg + t0 + vc * 8);
      int swv = vr & 15;
      *(uint2*)(Vs + vr * 64 + (((vc * 2)     ^ swv) << 2)) = make_uint2(vu.x, vu.y);
      *(uint2*)(Vs + vr * 64 + (((vc * 2 + 1) ^ swv) << 2)) = make_uint2(vu.z, vu.w);
    }
    __syncthreads();
#pragma unroll
    for (int mp = 0; mp < 2; mp++) {
      // K x32 A-frags for the two 16-k sub-slices of this 32-k window
      int krA = (mp * 2) * 16 + l15;
      int krB = krA + 16;
      const u16* kpA = Ks + krA * 32;
      const u16* kpB = Ks + krB * 32;
      int swkA = (krA >> 1) & 7;
      int swkB = (krB >> 1) & 7;
      uint2 a0A = *(const uint2*)(kpA + ((l4       ^ swkA) << 2));
      uint2 a1A = *(const uint2*)(kpA + (((4 + l4) ^ swkA) << 2));
      uint2 a0B = *(const uint2*)(kpB + ((l4       ^ swkB) << 2));
      uint2 a1B = *(const uint2*)(kpB + (((4 + l4) ^ swkB) << 2));
      f16x8 a8A = __builtin_bit_cast(f16x8, make_uint4(a0A.x, a0A.y, a1A.x, a1A.y));
      f16x8 a8B = __builtin_bit_cast(f16x8, make_uint4(a0B.x, a0B.y, a1B.x, a1B.y));
      // V^T x32 A-frags: k halves from sub-slices mtA, mtB
      int gA = mp * 8 + l4;
      int gB = gA + 4;
      uint2 vA0 = *(const uint2*)(Vs + l15 * 64        + ((gA ^ l15) << 2));
      uint2 vB0 = *(const uint2*)(Vs + l15 * 64        + ((gB ^ l15) << 2));
      uint2 vA1 = *(const uint2*)(Vs + (16 + l15) * 64 + ((gA ^ l15) << 2));
      uint2 vB1 = *(const uint2*)(Vs + (16 + l15) * 64 + ((gB ^ l15) << 2));
      f16x8 v80 = __builtin_bit_cast(f16x8, make_uint4(vA0.x, vA0.y, vB0.x, vB0.y));
      f16x8 v81 = __builtin_bit_cast(f16x8, make_uint4(vA1.x, vA1.y, vB1.x, vB1.y));
#pragma unroll
      for (int nt = 0; nt < 4; nt++) {
        f16x8 qb = __builtin_bit_cast(f16x8, qf8[nt]);
        f32x4 z = {0.f, 0.f, 0.f, 0.f};
        f32x4 sA = mfma32(a8A, qb, z);
        f32x4 sB = mfma32(a8B, qb, z);
        float e0 = __builtin_amdgcn_exp2f(sA[0]);
        float e1 = __builtin_amdgcn_exp2f(sA[1]);
        float e2 = __builtin_amdgcn_exp2f(sA[2]);
        float e3 = __builtin_amdgcn_exp2f(sA[3]);
        float e4 = __builtin_amdgcn_exp2f(sB[0]);
        float e5 = __builtin_amdgcn_exp2f(sB[1]);
        float e6 = __builtin_amdgcn_exp2f(sB[2]);
        float e7 = __builtin_amdgcn_exp2f(sB[3]);
        uint4 pu = make_uint4(
            __builtin_bit_cast(u32, __builtin_amdgcn_cvt_pkrtz(e0, e1)),
            __builtin_bit_cast(u32, __builtin_amdgcn_cvt_pkrtz(e2, e3)),
            __builtin_bit_cast(u32, __builtin_amdgcn_cvt_pkrtz(e4, e5)),
            __builtin_bit_cast(u32, __builtin_amdgcn_cvt_pkrtz(e6, e7)));
        f16x8 pb = __builtin_bit_cast(f16x8, pu);
        LS[nt]   = mfma32(ones8, pb, LS[nt]);
        O[0][nt] = mfma32(v80, pb, O[0][nt]);
        O[1][nt] = mfma32(v81, pb, O[1][nt]);
      }
    }
  }
  // store att (overwrites this block's own q-rows / h-col slice only)
#pragma unroll
  for (int nt = 0; nt < 4; nt++) {
    float r = 1.f / LS[nt][0];
#pragma unroll
    for (int mt2 = 0; mt2 < 2; mt2++) {
      uint2 ov = make_uint2(pack2h(O[mt2][nt][0] * r, O[mt2][nt][1] * r),
                            pack2h(O[mt2][nt][2] * r, O[mt2][nt][3] * r));
      *(uint2*)(wq_att + (tbase + q0 + nt * 16 + l15) * 128 + h * 32 + mt2 * 16 + l4 * 4) = ov;
    }
  }
}

// ---------------------------------------------------------------------------
// Output projection (att @ Wo^T + bo) * cm, scatter-add into out (=agg).
__global__ __launch_bounds__(256) void proj_k(
    const u16* __restrict__ watt, const u16* __restrict__ bp, const float* __restrict__ bo,
    const int* __restrict__ pidx, const float* __restrict__ cm, float* __restrict__ out) {
  __shared__ uint4 As[64 * 16];
  __shared__ int pis[64];
  __shared__ float cms[64];
  int tid = threadIdx.x;
  int t0 = blockIdx.x * 64;
  {
    int r = tid >> 2, qd = tid & 3;
    int T = t0 + r;
    int b = T / PS_;
    int ps = T - b * PS_;
    if (qd == 0) { pis[r] = b * N_ + pidx[ps]; cms[r] = cm[ps]; }
    const uint4* src = (const uint4*)(watt + (size_t)T * D_ + qd * 32);
#pragma unroll
    for (int c = 0; c < 4; c++) {
      int byteoff = (qd * 64 + c * 16) ^ ((r & 7) << 4);
      As[r * 16 + (byteoff >> 4)] = src[c];
    }
  }
  __syncthreads();
  int lane = tid & 63, wid = tid >> 6;
  int l15 = lane & 15, l4 = lane >> 4;
  int wm = wid & 1, wn = wid >> 1;
  uint2 bfrag[4][8];
  const uint2* bpp = (const uint2*)bp;
#pragma unroll
  for (int nt = 0; nt < 4; nt++) {
    int ntg = wn * 4 + nt;
#pragma unroll
    for (int ks = 0; ks < 8; ks++)
      bfrag[nt][ks] = bpp[(3 * 64 + ntg * 8 + ks) * 64 + lane];
  }
  f32x4 acc[2][4];
#pragma unroll
  for (int mt = 0; mt < 2; mt++)
#pragma unroll
    for (int nt = 0; nt < 4; nt++) {
      f32x4 z = {0.f, 0.f, 0.f, 0.f};
      acc[mt][nt] = z;
    }
  uint2 afr[2][8];
#pragma unroll
  for (int mt = 0; mt < 2; mt++) {
    int row = wm * 32 + mt * 16 + l15;
#pragma unroll
    for (int ks = 0; ks < 8; ks++) {
      int byteoff = (ks * 32 + (l4 << 3)) ^ ((row & 7) << 4);
      afr[mt][ks] = *(const uint2*)((const char*)As + row * 256 + byteoff);
    }
  }
#pragma unroll
  for (int ks = 0; ks < 8; ks++) {
#pragma unroll
    for (int mt = 0; mt < 2; mt++) {
      f16x4 a = __builtin_bit_cast(f16x4, afr[mt][ks]);
#pragma unroll
      for (int nt = 0; nt < 4; nt++) {
        f16x4 b = __builtin_bit_cast(f16x4, bfrag[nt][ks]);
        acc[mt][nt] = __builtin_amdgcn_mfma_f32_16x16x16f16(a, b, acc[mt][nt], 0, 0, 0);
      }
    }
  }
#pragma unroll
  for (int mt = 0; mt < 2; mt++) {
    int rl = wm * 32 + mt * 16 + (l4 << 2);
#pragma unroll
    for (int nt = 0; nt < 4; nt++) {
      int col = wn * 64 + nt * 16 + l15;
      float bov = bo[col];
#pragma unroll
      for (int i = 0; i < 4; i++) {
        float cmv = cms[rl + i];
        if (cmv != 0.f) {
          float val = (acc[mt][nt][i] + bov) * cmv;
          atomicAdd(out + (size_t)pis[rl + i] * D_ + col, val);
        }
      }
    }
  }
}

// ---------------------------------------------------------------------------
// h = x + agg/max(cnt,1); LayerNorm over D; in-place on out.
__global__ __launch_bounds__(256) void ln_k(
    const float* __restrict__ x, const float* __restrict__ cnt,
    const float* __restrict__ g, const float* __restrict__ bta, float* __restrict__ out) {
  int tid = threadIdx.x;
  int row = blockIdx.x * 8 + (tid >> 5);
  if (row >= B_ * N_) return;
  int l32 = tid & 31;
  int n = row % N_;
  float c = cnt[n];
  c = c > 1.f ? c : 1.f;
  float rc = 1.f / c;
  size_t off = (size_t)row * D_ + l32 * 4;
  float4 xa = *(const float4*)(x + off);
  float4 ag = *(const float4*)(out + off);
  float4 hv = make_float4(fmaf(ag.x, rc, xa.x), fmaf(ag.y, rc, xa.y),
                          fmaf(ag.z, rc, xa.z), fmaf(ag.w, rc, xa.w));
  float s = hv.x + hv.y + hv.z + hv.w;
  float s2 = hv.x * hv.x + hv.y * hv.y + hv.z * hv.z + hv.w * hv.w;
#pragma unroll
  for (int m = 16; m >= 1; m >>= 1) {
    s += __shfl_xor(s, m);
    s2 += __shfl_xor(s2, m);
  }
  float mu = s * 0.0078125f;
  float var = s2 * 0.0078125f - mu * mu;
  float rstd = rsqrtf(var + 1e-5f);
  float4 gv = *(const float4*)(g + l32 * 4);
  float4 bv = *(const float4*)(bta + l32 * 4);
  float4 ov = make_float4((hv.x - mu) * rstd * gv.x + bv.x,
                          (hv.y - mu) * rstd * gv.y + bv.y,
                          (hv.z - mu) * rstd * gv.z + bv.z,
                          (hv.w - mu) * rstd * gv.w + bv.w);
  *(float4*)(out + off) = ov;
}

// ---------------------------------------------------------------------------
extern "C" void kernel_launch(void* const* d_in, const int* in_sizes, int n_in,
                              void* d_out, int out_size, void* d_ws, size_t ws_size,
                              hipStream_t stream) {
  const float* x   = (const float*)d_in[0];
  const float* Wq  = (const float*)d_in[1];
  const float* bq  = (const float*)d_in[2];
  const float* Wk  = (const float*)d_in[3];
  const float* bk  = (const float*)d_in[4];
  const float* Wv  = (const float*)d_in[5];
  const float* bv  = (const float*)d_in[6];
  const float* Wo  = (const float*)d_in[7];
  const float* bo  = (const float*)d_in[8];
  const float* lng = (const float*)d_in[9];
  const float* lnb = (const float*)d_in[10];
  const int* pidx  = (const int*)d_in[11];
  const void* cmask = d_in[12];
  float* out = (float*)d_out;
  char* ws = (char*)d_ws;

  u16* wsq = (u16*)(ws + OFF_Q);
  u16* wsk = (u16*)(ws + OFF_K);
  u16* wsvt = (u16*)(ws + OFF_V);
  u16* wbp = (u16*)(ws + OFF_BP);
  float* wcnt = (float*)(ws + OFF_CNT);
  float* wcm  = (float*)(ws + OFF_CM);
  int* wflag  = (int*)(ws + OFF_FLAG);

  hipMemsetAsync(d_out, 0, (size_t)out_size * sizeof(float), stream);
  hipMemsetAsync(ws + OFF_CNT, 0, (OFF_FLAG + 4) - OFF_CNT, stream);

  probe_mask_k<<<1, 256, 0, stream>>>((const unsigned char*)cmask, wflag);
  mask_cnt_k<<<200, 256, 0, stream>>>(cmask, pidx, wflag, wcm, wcnt);
  pack_w_k<<<64, 256, 0, stream>>>(Wq, Wk, Wv, Wo, wbp);
  qkv_k<<<1600, 256, 0, stream>>>(x, pidx, wbp, bq, bk, bv, wsq);
  attn_k<<<800, 512, 0, stream>>>(wsq, wsk, wsvt);
  proj_k<<<1600, 256, 0, stream>>>(wsq, wbp, bo, pidx, wcm, out);
  ln_k<<<10241, 256, 0, stream>>>(x, wcnt, lng, lnb, out);
}

// Round 6
// 207.001 us; speedup vs baseline: 2.9345x; 1.0087x over previous
//
#include <hip/hip_runtime.h>
#include <hip/hip_bf16.h>
#include <hip/hip_fp16.h>

// Problem constants
#define B_ 2
#define N_ 40962
#define D_ 128
#define H_ 4
#define P_ 100
#define S_ 512
#define T_ 102400      // B*P*S tokens
#define PS_ 51200      // P*S

typedef unsigned short u16;
typedef unsigned int u32;
typedef _Float16 f16x4 __attribute__((ext_vector_type(4)));
typedef _Float16 f16x8 __attribute__((ext_vector_type(8)));
typedef float f32x4 __attribute__((ext_vector_type(4)));

// Workspace byte offsets (total ~79.2 MB)
#define OFF_Q    0ull           // q fp16 [T][128]  (later reused as att)
#define OFF_K    26214400ull    // k fp16 per-head: [bp*4+h][512][32]
#define OFF_V    52428800ull    // v fp16 V^T: [bp*4+h][32][512]
#define OFF_BP   78643200ull    // packed W frags: 4 mats x 4096 lane-frags x 8B
#define OFF_CNT  78774272ull    // float cnt[N]
#define OFF_CM   78938120ull    // float cm[P*S]
#define OFF_FLAG 79142920ull    // int dtype flag for core_mask

__device__ __forceinline__ u32 pack2h(float a, float b) {
  __half2 h = __floats2half2_rn(a, b);
  return __builtin_bit_cast(u32, h);
}
__device__ __forceinline__ f16x8 cat8(uint2 lo, uint2 hi) {
  return __builtin_bit_cast(f16x8, make_uint4(lo.x, lo.y, hi.x, hi.y));
}

// 16x16x32 f16 MFMA; x32 frag = concat of two x16 half-frags (k 0..15, 16..31).
__device__ __forceinline__ f32x4 mfma32(f16x8 a, f16x8 b, f32x4 c) {
#if __has_builtin(__builtin_amdgcn_mfma_f32_16x16x32_f16)
  return __builtin_amdgcn_mfma_f32_16x16x32_f16(a, b, c, 0, 0, 0);
#else
  f16x4 alo = {a[0], a[1], a[2], a[3]}, ahi = {a[4], a[5], a[6], a[7]};
  f16x4 blo = {b[0], b[1], b[2], b[3]}, bhi = {b[4], b[5], b[6], b[7]};
  c = __builtin_amdgcn_mfma_f32_16x16x16f16(alo, blo, c, 0, 0, 0);
  return __builtin_amdgcn_mfma_f32_16x16x16f16(ahi, bhi, c, 0, 0, 0);
#endif
}

// ---------------------------------------------------------------------------
// Probe core_mask storage format (bool8 / int32 / float32) — see round 0.
__global__ void probe_mask_k(const unsigned char* __restrict__ mb, int* __restrict__ flag) {
  int f = 0;
  for (int i = threadIdx.x; i < PS_; i += 256) {
    unsigned char v = mb[i];
    if (v) {
      int m4 = i & 3;
      if (m4 == 1) f |= 1;
      else if (m4 == 3) f |= 2;
    }
  }
  if (f) atomicOr(flag, f);
}

// cm[i] = mask as float; cnt[n] += cm
__global__ void mask_cnt_k(const void* __restrict__ mask, const int* __restrict__ pidx,
                           const int* __restrict__ flag, float* __restrict__ cm,
                           float* __restrict__ cnt) {
  int i = blockIdx.x * 256 + threadIdx.x;
  int fl = *flag;
  bool on;
  if (fl & 1)      on = ((const unsigned char*)mask)[i] != 0;
  else if (fl & 2) on = ((const float*)mask)[i] != 0.f;
  else             on = ((const int*)mask)[i] != 0;
  cm[i] = on ? 1.f : 0.f;
  if (on) atomicAdd(&cnt[pidx[i]], 1.f);
}

// ---------------------------------------------------------------------------
// Pack Wq/Wk/Wv/Wo into MFMA B-fragment order (fp16). See round 0.
__global__ void pack_w_k(const float* __restrict__ Wq, const float* __restrict__ Wk,
                         const float* __restrict__ Wv, const float* __restrict__ Wo,
                         u16* __restrict__ bp) {
  int gi = blockIdx.x * 256 + threadIdx.x;   // < 16384
  int m = gi >> 12;
  int r = gi & 4095;
  int fi = r >> 6;         // nt*8 + ks
  int l = r & 63;
  int nt = fi >> 3, ks = fi & 7;
  const float* W = (m == 0) ? Wq : (m == 1) ? Wk : (m == 2) ? Wv : Wo;
  int n = nt * 16 + (l & 15);
  int k0 = ks * 16 + ((l >> 4) << 2);
  float4 w = *(const float4*)(W + n * 128 + k0);
  *(uint2*)(bp + (size_t)gi * 4) = make_uint2(pack2h(w.x, w.y), pack2h(w.z, w.w));
}

// ---------------------------------------------------------------------------
// Gather px rows once + ALL THREE projections. mat 0 -> q [T][128];
// mat 1 -> K per-head [bp*4+h][s=512][hd=32]; mat 2 -> V^T [bp*4+h][32][512].
__global__ __launch_bounds__(256) void qkv_k(
    const float* __restrict__ x, const int* __restrict__ pidx,
    const u16* __restrict__ bp,
    const float* __restrict__ bq, const float* __restrict__ bk, const float* __restrict__ bv,
    u16* __restrict__ qkv) {
  __shared__ uint4 As[64 * 16];   // 64 rows x 128 fp16, XOR-swizzled
  int tid = threadIdx.x;
  int t0 = blockIdx.x * 64;
  {
    int r = tid >> 2, qd = tid & 3;
    int T = t0 + r;
    int b = T / PS_;
    int ps = T - b * PS_;
    int pi = pidx[ps];
    const float4* src = (const float4*)(x + ((size_t)b * N_ + pi) * D_ + qd * 32);
    u32 us[16];
#pragma unroll
    for (int j = 0; j < 8; j++) {
      float4 f = src[j];
      us[2 * j]     = pack2h(f.x, f.y);
      us[2 * j + 1] = pack2h(f.z, f.w);
    }
#pragma unroll
    for (int c = 0; c < 4; c++) {
      int byteoff = (qd * 64 + c * 16) ^ ((r & 7) << 4);
      As[r * 16 + (byteoff >> 4)] = make_uint4(us[4 * c], us[4 * c + 1], us[4 * c + 2], us[4 * c + 3]);
    }
  }
  __syncthreads();
  int lane = tid & 63, wid = tid >> 6;
  int l15 = lane & 15, l4 = lane >> 4;
  int wm = wid & 1, wn = wid >> 1;
  uint2 afr[2][8];
#pragma unroll
  for (int mt = 0; mt < 2; mt++) {
    int row = wm * 32 + mt * 16 + l15;
#pragma unroll
    for (int ks = 0; ks < 8; ks++) {
      int byteoff = (ks * 32 + (l4 << 3)) ^ ((row & 7) << 4);
      afr[mt][ks] = *(const uint2*)((const char*)As + row * 256 + byteoff);
    }
  }
  const uint2* bpp = (const uint2*)bp;
#pragma unroll 1
  for (int mat = 0; mat < 3; mat++) {
    uint2 bfrag[4][8];
#pragma unroll
    for (int nt = 0; nt < 4; nt++) {
      int ntg = wn * 4 + nt;
#pragma unroll
      for (int ks = 0; ks < 8; ks++)
        bfrag[nt][ks] = bpp[(mat * 64 + ntg * 8 + ks) * 64 + lane];
    }
    const float* bias = (mat == 0) ? bq : (mat == 1) ? bk : bv;
    f32x4 acc[2][4];
#pragma unroll
    for (int nt = 0; nt < 4; nt++) {
      float bvv = bias[wn * 64 + nt * 16 + l15];
#pragma unroll
      for (int mt = 0; mt < 2; mt++) {
        f32x4 z = {bvv, bvv, bvv, bvv};
        acc[mt][nt] = z;
      }
    }
#pragma unroll
    for (int kp = 0; kp < 4; kp++) {
#pragma unroll
      for (int mt = 0; mt < 2; mt++) {
        f16x8 a = cat8(afr[mt][2 * kp], afr[mt][2 * kp + 1]);
#pragma unroll
        for (int nt = 0; nt < 4; nt++) {
          f16x8 b = cat8(bfrag[nt][2 * kp], bfrag[nt][2 * kp + 1]);
          acc[mt][nt] = mfma32(a, b, acc[mt][nt]);
        }
      }
    }
    if (mat == 2) {
      u16* vt = qkv + (size_t)2 * T_ * D_;
#pragma unroll
      for (int mt = 0; mt < 2; mt++) {
        int rbase = t0 + wm * 32 + mt * 16 + (l4 << 2);
        int bpi = rbase >> 9;        // b*P + p (same for all 4 i)
        int s = rbase & 511;
#pragma unroll
        for (int nt = 0; nt < 4; nt++) {
          int col = wn * 64 + nt * 16 + l15;
          uint2 pv = make_uint2(pack2h(acc[mt][nt][0], acc[mt][nt][1]),
                                pack2h(acc[mt][nt][2], acc[mt][nt][3]));
          *(uint2*)(vt + ((size_t)(bpi * 4 + (col >> 5)) * 32 + (col & 31)) * 512 + s) = pv;
        }
      }
    } else if (mat == 1) {
      u16* kh = qkv + (size_t)T_ * D_;
#pragma unroll
      for (int mt = 0; mt < 2; mt++) {
        int rbase = t0 + wm * 32 + mt * 16 + (l4 << 2);
        int bpi = rbase >> 9;
        int s = rbase & 511;
#pragma unroll
        for (int nt = 0; nt < 4; nt++) {
          int col = wn * 64 + nt * 16 + l15;
          int hd = col & 31, ch = col >> 5;
#pragma unroll
          for (int i = 0; i < 4; i++) {
            __half hv = __float2half(acc[mt][nt][i]);
            kh[((size_t)(bpi * 4 + ch) * 512 + (s + i)) * 32 + hd] = __builtin_bit_cast(u16, hv);
          }
        }
      }
    } else {
      u16* outp = qkv;
#pragma unroll
      for (int mt = 0; mt < 2; mt++) {
        int rbase = t0 + wm * 32 + mt * 16 + (l4 << 2);
#pragma unroll
        for (int nt = 0; nt < 4; nt++) {
          int col = wn * 64 + nt * 16 + l15;
#pragma unroll
          for (int i = 0; i < 4; i++) {
            __half hv = __float2half(acc[mt][nt][i]);
            outp[(size_t)(rbase + i) * D_ + col] = __builtin_bit_cast(u16, hv);
          }
        }
      }
    }
  }
}

// ---------------------------------------------------------------------------
// MFMA flash-attention, swapped operands, x32 MFMA. One block = (bp, h),
// 512 threads / 8 waves. The ENTIRE K (512x32) and V^T (32x512) for this
// (bp,h) are staged into LDS once (64 KB) -> ONE barrier per block, zero in
// the main loop; waves free-run across the 8 k-tiles.
__global__ __launch_bounds__(512, 4) void attn_k(
    u16* wq_att, const u16* __restrict__ wk, const u16* __restrict__ wvt) {
  __shared__ __align__(16) u16 Ks[512 * 32];  // [k][32 hd], 8B-granule swizzle
  __shared__ __align__(16) u16 Vs[32 * 512];  // [hd][512 k], 8B-granule swizzle
  int tid = threadIdx.x;
  int bid = blockIdx.x;
  int h = bid & 3;
  int bp = bid >> 2;
  int lane = tid & 63, w = tid >> 6;
  int l15 = lane & 15, l4 = lane >> 4;
  size_t tbase = (size_t)bp * 512;
  int q0 = w * 64;
  // stage whole K (contiguous per-head) and V^T (contiguous)
  {
    const u16* kg = wk + (size_t)(bp * 4 + h) * 512 * 32;
    const u16* vg = wvt + (size_t)(bp * 4 + h) * 32 * 512;
#pragma unroll
    for (int j = 0; j < 4; j++) {
      int i = j * 512 + tid;
      uint4 ku = *(const uint4*)(kg + (size_t)i * 8);
      int row = i >> 2, c = i & 3;
      int swk = (row >> 1) & 7;
      *(uint2*)(Ks + row * 32 + (((2 * c)     ^ swk) << 2)) = make_uint2(ku.x, ku.y);
      *(uint2*)(Ks + row * 32 + (((2 * c + 1) ^ swk) << 2)) = make_uint2(ku.z, ku.w);
      uint4 vu = *(const uint4*)(vg + (size_t)i * 8);
      int vr2 = i >> 6, vc = i & 63;
      int swv = vr2 & 15;
      *(uint2*)(Vs + vr2 * 512 + (((2 * vc)     ^ swv) << 2)) = make_uint2(vu.x, vu.y);
      *(uint2*)(Vs + vr2 * 512 + (((2 * vc + 1) ^ swv) << 2)) = make_uint2(vu.z, vu.w);
    }
  }
  // Q B-frags (x32: elems 0-3 = hd 4*l4..+3, elems 4-7 = hd 16+4*l4..+3),
  // pre-scaled by log2(e)/sqrt(32).
  uint4 qf8[4];
  {
    const u16* qbase = wq_att + (tbase + q0) * 128 + h * 32;
    const __half2 sc2 = __floats2half2_rn(0.25500527f, 0.25500527f);
#pragma unroll
    for (int nt = 0; nt < 4; nt++) {
      const u16* qr = qbase + (size_t)(nt * 16 + l15) * 128 + l4 * 4;
      uint2 u0 = *(const uint2*)(qr);
      uint2 u1 = *(const uint2*)(qr + 16);
      u32 w0 = __builtin_bit_cast(u32, __hmul2(__builtin_bit_cast(__half2, u0.x), sc2));
      u32 w1 = __builtin_bit_cast(u32, __hmul2(__builtin_bit_cast(__half2, u0.y), sc2));
      u32 w2 = __builtin_bit_cast(u32, __hmul2(__builtin_bit_cast(__half2, u1.x), sc2));
      u32 w3 = __builtin_bit_cast(u32, __hmul2(__builtin_bit_cast(__half2, u1.y), sc2));
      qf8[nt] = make_uint4(w0, w1, w2, w3);
    }
  }
  f32x4 O[2][4];
  f32x4 LS[4];
#pragma unroll
  for (int a = 0; a < 4; a++) {
    O[0][a] = (f32x4){0.f, 0.f, 0.f, 0.f};
    O[1][a] = (f32x4){0.f, 0.f, 0.f, 0.f};
    LS[a] = (f32x4){0.f, 0.f, 0.f, 0.f};
  }
  const f16x8 ones8 = {(_Float16)1.f, (_Float16)1.f, (_Float16)1.f, (_Float16)1.f,
                       (_Float16)1.f, (_Float16)1.f, (_Float16)1.f, (_Float16)1.f};
  __syncthreads();   // the only barrier

  for (int t0 = 0; t0 < 512; t0 += 64) {
#pragma unroll
    for (int mp = 0; mp < 2; mp++) {
      int krA = t0 + mp * 32 + l15;
      int krB = krA + 16;
      const u16* kpA = Ks + krA * 32;
      const u16* kpB = Ks + krB * 32;
      int swkA = (krA >> 1) & 7;
      int swkB = (krB >> 1) & 7;
      uint2 a0A = *(const uint2*)(kpA + ((l4       ^ swkA) << 2));
      uint2 a1A = *(const uint2*)(kpA + (((4 + l4) ^ swkA) << 2));
      uint2 a0B = *(const uint2*)(kpB + ((l4       ^ swkB) << 2));
      uint2 a1B = *(const uint2*)(kpB + (((4 + l4) ^ swkB) << 2));
      f16x8 a8A = cat8(a0A, a1A);
      f16x8 a8B = cat8(a0B, a1B);
      int gA = (t0 >> 2) + mp * 8 + l4;
      int gB = gA + 4;
      uint2 vA0 = *(const uint2*)(Vs + l15 * 512        + ((gA ^ l15) << 2));
      uint2 vB0 = *(const uint2*)(Vs + l15 * 512        + ((gB ^ l15) << 2));
      uint2 vA1 = *(const uint2*)(Vs + (16 + l15) * 512 + ((gA ^ l15) << 2));
      uint2 vB1 = *(const uint2*)(Vs + (16 + l15) * 512 + ((gB ^ l15) << 2));
      f16x8 v80 = cat8(vA0, vB0);
      f16x8 v81 = cat8(vA1, vB1);
#pragma unroll
      for (int nt = 0; nt < 4; nt++) {
        f16x8 qb = __builtin_bit_cast(f16x8, qf8[nt]);
        f32x4 z = {0.f, 0.f, 0.f, 0.f};
        f32x4 sA = mfma32(a8A, qb, z);
        f32x4 sB = mfma32(a8B, qb, z);
        float e0 = __builtin_amdgcn_exp2f(sA[0]);
        float e1 = __builtin_amdgcn_exp2f(sA[1]);
        float e2 = __builtin_amdgcn_exp2f(sA[2]);
        float e3 = __builtin_amdgcn_exp2f(sA[3]);
        float e4 = __builtin_amdgcn_exp2f(sB[0]);
        float e5 = __builtin_amdgcn_exp2f(sB[1]);
        float e6 = __builtin_amdgcn_exp2f(sB[2]);
        float e7 = __builtin_amdgcn_exp2f(sB[3]);
        uint4 pu = make_uint4(
            __builtin_bit_cast(u32, __builtin_amdgcn_cvt_pkrtz(e0, e1)),
            __builtin_bit_cast(u32, __builtin_amdgcn_cvt_pkrtz(e2, e3)),
            __builtin_bit_cast(u32, __builtin_amdgcn_cvt_pkrtz(e4, e5)),
            __builtin_bit_cast(u32, __builtin_amdgcn_cvt_pkrtz(e6, e7)));
        f16x8 pb = __builtin_bit_cast(f16x8, pu);
        LS[nt]   = mfma32(ones8, pb, LS[nt]);
        O[0][nt] = mfma32(v80, pb, O[0][nt]);
        O[1][nt] = mfma32(v81, pb, O[1][nt]);
      }
    }
  }
  // store att (overwrites this block's own q-rows / h-col slice only)
#pragma unroll
  for (int nt = 0; nt < 4; nt++) {
    float r = 1.f / LS[nt][0];
#pragma unroll
    for (int mt2 = 0; mt2 < 2; mt2++) {
      uint2 ov = make_uint2(pack2h(O[mt2][nt][0] * r, O[mt2][nt][1] * r),
                            pack2h(O[mt2][nt][2] * r, O[mt2][nt][3] * r));
      *(uint2*)(wq_att + (tbase + q0 + nt * 16 + l15) * 128 + h * 32 + mt2 * 16 + l4 * 4) = ov;
    }
  }
}

// ---------------------------------------------------------------------------
// Output projection (att @ Wo^T + bo) * cm, scatter-add into out (=agg).
__global__ __launch_bounds__(256) void proj_k(
    const u16* __restrict__ watt, const u16* __restrict__ bp, const float* __restrict__ bo,
    const int* __restrict__ pidx, const float* __restrict__ cm, float* __restrict__ out) {
  __shared__ uint4 As[64 * 16];
  __shared__ int pis[64];
  __shared__ float cms[64];
  int tid = threadIdx.x;
  int t0 = blockIdx.x * 64;
  {
    int r = tid >> 2, qd = tid & 3;
    int T = t0 + r;
    int b = T / PS_;
    int ps = T - b * PS_;
    if (qd == 0) { pis[r] = b * N_ + pidx[ps]; cms[r] = cm[ps]; }
    const uint4* src = (const uint4*)(watt + (size_t)T * D_ + qd * 32);
#pragma unroll
    for (int c = 0; c < 4; c++) {
      int byteoff = (qd * 64 + c * 16) ^ ((r & 7) << 4);
      As[r * 16 + (byteoff >> 4)] = src[c];
    }
  }
  __syncthreads();
  int lane = tid & 63, wid = tid >> 6;
  int l15 = lane & 15, l4 = lane >> 4;
  int wm = wid & 1, wn = wid >> 1;
  uint2 bfrag[4][8];
  const uint2* bpp = (const uint2*)bp;
#pragma unroll
  for (int nt = 0; nt < 4; nt++) {
    int ntg = wn * 4 + nt;
#pragma unroll
    for (int ks = 0; ks < 8; ks++)
      bfrag[nt][ks] = bpp[(3 * 64 + ntg * 8 + ks) * 64 + lane];
  }
  f32x4 acc[2][4];
#pragma unroll
  for (int mt = 0; mt < 2; mt++)
#pragma unroll
    for (int nt = 0; nt < 4; nt++) {
      f32x4 z = {0.f, 0.f, 0.f, 0.f};
      acc[mt][nt] = z;
    }
  uint2 afr[2][8];
#pragma unroll
  for (int mt = 0; mt < 2; mt++) {
    int row = wm * 32 + mt * 16 + l15;
#pragma unroll
    for (int ks = 0; ks < 8; ks++) {
      int byteoff = (ks * 32 + (l4 << 3)) ^ ((row & 7) << 4);
      afr[mt][ks] = *(const uint2*)((const char*)As + row * 256 + byteoff);
    }
  }
#pragma unroll
  for (int kp = 0; kp < 4; kp++) {
#pragma unroll
    for (int mt = 0; mt < 2; mt++) {
      f16x8 a = cat8(afr[mt][2 * kp], afr[mt][2 * kp + 1]);
#pragma unroll
      for (int nt = 0; nt < 4; nt++) {
        f16x8 b = cat8(bfrag[nt][2 * kp], bfrag[nt][2 * kp + 1]);
        acc[mt][nt] = mfma32(a, b, acc[mt][nt]);
      }
    }
  }
#pragma unroll
  for (int mt = 0; mt < 2; mt++) {
    int rl = wm * 32 + mt * 16 + (l4 << 2);
#pragma unroll
    for (int nt = 0; nt < 4; nt++) {
      int col = wn * 64 + nt * 16 + l15;
      float bov = bo[col];
#pragma unroll
      for (int i = 0; i < 4; i++) {
        float cmv = cms[rl + i];
        if (cmv != 0.f) {
          float val = (acc[mt][nt][i] + bov) * cmv;
          atomicAdd(out + (size_t)pis[rl + i] * D_ + col, val);
        }
      }
    }
  }
}

// ---------------------------------------------------------------------------
// h = x + agg/max(cnt,1); LayerNorm over D; in-place on out.
__global__ __launch_bounds__(256) void ln_k(
    const float* __restrict__ x, const float* __restrict__ cnt,
    const float* __restrict__ g, const float* __restrict__ bta, float* __restrict__ out) {
  int tid = threadIdx.x;
  int row = blockIdx.x * 8 + (tid >> 5);
  if (row >= B_ * N_) return;
  int l32 = tid & 31;
  int n = row % N_;
  float c = cnt[n];
  c = c > 1.f ? c : 1.f;
  float rc = 1.f / c;
  size_t off = (size_t)row * D_ + l32 * 4;
  float4 xa = *(const float4*)(x + off);
  float4 ag = *(const float4*)(out + off);
  float4 hv = make_float4(fmaf(ag.x, rc, xa.x), fmaf(ag.y, rc, xa.y),
                          fmaf(ag.z, rc, xa.z), fmaf(ag.w, rc, xa.w));
  float s = hv.x + hv.y + hv.z + hv.w;
  float s2 = hv.x * hv.x + hv.y * hv.y + hv.z * hv.z + hv.w * hv.w;
#pragma unroll
  for (int m = 16; m >= 1; m >>= 1) {
    s += __shfl_xor(s, m);
    s2 += __shfl_xor(s2, m);
  }
  float mu = s * 0.0078125f;
  float var = s2 * 0.0078125f - mu * mu;
  float rstd = rsqrtf(var + 1e-5f);
  float4 gv = *(const float4*)(g + l32 * 4);
  float4 bv = *(const float4*)(bta + l32 * 4);
  float4 ov = make_float4((hv.x - mu) * rstd * gv.x + bv.x,
                          (hv.y - mu) * rstd * gv.y + bv.y,
                          (hv.z - mu) * rstd * gv.z + bv.z,
                          (hv.w - mu) * rstd * gv.w + bv.w);
  *(float4*)(out + off) = ov;
}

// ---------------------------------------------------------------------------
extern "C" void kernel_launch(void* const* d_in, const int* in_sizes, int n_in,
                              void* d_out, int out_size, void* d_ws, size_t ws_size,
                              hipStream_t stream) {
  const float* x   = (const float*)d_in[0];
  const float* Wq  = (const float*)d_in[1];
  const float* bq  = (const float*)d_in[2];
  const float* Wk  = (const float*)d_in[3];
  const float* bk  = (const float*)d_in[4];
  const float* Wv  = (const float*)d_in[5];
  const float* bv  = (const float*)d_in[6];
  const float* Wo  = (const float*)d_in[7];
  const float* bo  = (const float*)d_in[8];
  const float* lng = (const float*)d_in[9];
  const float* lnb = (const float*)d_in[10];
  const int* pidx  = (const int*)d_in[11];
  const void* cmask = d_in[12];
  float* out = (float*)d_out;
  char* ws = (char*)d_ws;

  u16* wsq = (u16*)(ws + OFF_Q);
  u16* wsk = (u16*)(ws + OFF_K);
  u16* wsvt = (u16*)(ws + OFF_V);
  u16* wbp = (u16*)(ws + OFF_BP);
  float* wcnt = (float*)(ws + OFF_CNT);
  float* wcm  = (float*)(ws + OFF_CM);
  int* wflag  = (int*)(ws + OFF_FLAG);

  hipMemsetAsync(d_out, 0, (size_t)out_size * sizeof(float), stream);
  hipMemsetAsync(ws + OFF_CNT, 0, (OFF_FLAG + 4) - OFF_CNT, stream);

  probe_mask_k<<<1, 256, 0, stream>>>((const unsigned char*)cmask, wflag);
  mask_cnt_k<<<200, 256, 0, stream>>>(cmask, pidx, wflag, wcm, wcnt);
  pack_w_k<<<64, 256, 0, stream>>>(Wq, Wk, Wv, Wo, wbp);
  qkv_k<<<1600, 256, 0, stream>>>(x, pidx, wbp, bq, bk, bv, wsq);
  attn_k<<<800, 512, 0, stream>>>(wsq, wsk, wsvt);
  proj_k<<<1600, 256, 0, stream>>>(wsq, wbp, bo, pidx, wcm, out);
  ln_k<<<10241, 256, 0, stream>>>(x, wcnt, lng, lnb, out);
}